// Round 3
// baseline (653.030 us; speedup 1.0000x reference)
//
#include <hip/hip_runtime.h>
#include <stdint.h>

#define N_NODES 50000
#define N_EDGES 500000
#define NPAD    50048   // 391 * 128

typedef _Float16 half8_ __attribute__((ext_vector_type(8)));
typedef _Float16 half4_ __attribute__((ext_vector_type(4)));
typedef float    float4_ __attribute__((ext_vector_type(4)));

// ---------------- CSR build ----------------
__global__ void count_kernel(const int* __restrict__ dst, int* __restrict__ cnt, int e) {
    int i = blockIdx.x * 256 + threadIdx.x;
    if (i < e) atomicAdd(&cnt[dst[i]], 1);
}

__global__ void scan_kernel(const int* __restrict__ cnt, int* __restrict__ rowptr,
                            int* __restrict__ cursor, int n) {
    __shared__ int sm[1024];
    __shared__ int sm2[1024];
    __shared__ int carry;
    int t = threadIdx.x;
    if (t == 0) carry = 0;
    __syncthreads();
    int* bufs[2] = { sm, sm2 };
    for (int base = 0; base < n; base += 1024) {
        int v = (base + t < n) ? cnt[base + t] : 0;
        int cur = 0;
        bufs[0][t] = v;
        __syncthreads();
        for (int off = 1; off < 1024; off <<= 1) {
            int* s = bufs[cur]; int* d = bufs[cur ^ 1];
            int x = s[t];
            if (t >= off) x += s[t - off];
            d[t] = x;
            __syncthreads();
            cur ^= 1;
        }
        int incl = bufs[cur][t];
        int excl = incl - v + carry;
        if (base + t < n) { rowptr[base + t] = excl; cursor[base + t] = excl; }
        __syncthreads();
        if (t == 1023) carry += incl;
        __syncthreads();
    }
    if (t == 0) rowptr[n] = carry;
}

__global__ void fill_kernel(const int* __restrict__ dst, const int* __restrict__ src,
                            int* __restrict__ cursor, int* __restrict__ col, int e) {
    int i = blockIdx.x * 256 + threadIdx.x;
    if (i < e) {
        int p = atomicAdd(&cursor[dst[i]], 1);
        col[p] = src[i];
    }
}

// ---------------- staging ----------------
// x (fp32) -> fp16 into A columns [256,512) and [512,768)
__global__ void copyx_kernel(const float* __restrict__ x, _Float16* __restrict__ A, int n) {
    int i = blockIdx.x * 256 + threadIdx.x;
    if (i >= n * 64) return;
    int nd = i >> 6, l = i & 63;
    float4_ v = *(const float4_*)(x + (size_t)nd * 256 + l * 4);
    half4_ h;
    h[0] = (_Float16)v[0]; h[1] = (_Float16)v[1];
    h[2] = (_Float16)v[2]; h[3] = (_Float16)v[3];
    *(half4_*)(A + (size_t)nd * 768 + 256 + l * 4) = h;
    *(half4_*)(A + (size_t)nd * 768 + 512 + l * 4) = h;
}

// zero the padded rows of A (768 wide) and h2 (256 wide)
__global__ void pad_kernel(_Float16* __restrict__ A, _Float16* __restrict__ h2) {
    int i = blockIdx.x * 256 + threadIdx.x;
    half4_ z = {(_Float16)0.f, (_Float16)0.f, (_Float16)0.f, (_Float16)0.f};
    if (i < 9216) {                        // 48 rows * 768 / 4
        *(half4_*)(A + (size_t)N_NODES * 768 + (size_t)i * 4) = z;
    } else if (i < 12288) {                // + 48 rows * 256 / 4
        *(half4_*)(h2 + (size_t)N_NODES * 256 + (size_t)(i - 9216) * 4) = z;
    }
}

// Wcat[l][j][0:768] = [Wl[l][j] | W0[l][j] | W1[l][j]] as fp16; then Wout as fp16.
__global__ void wcat_kernel(const float* __restrict__ Wl, const float* __restrict__ W0,
                            const float* __restrict__ W1, const float* __restrict__ Wout,
                            _Float16* __restrict__ Wcat) {
    int i = blockIdx.x * 256 + threadIdx.x;
    if (i < 2 * 256 * 768) {
        int l = i / (256 * 768);
        int r = i % (256 * 768);
        int j = r / 768, k = r % 768;
        const float* s = (k < 256) ? Wl : (k < 512 ? W0 : W1);
        Wcat[i] = (_Float16)s[l * 65536 + j * 256 + (k & 255)];
    } else if (i < 2 * 256 * 768 + 128 * 256) {
        int r = i - 2 * 256 * 768;
        Wcat[i] = (_Float16)Wout[r];
    }
}

__global__ void bias_kernel(const float* __restrict__ bl, const float* __restrict__ b0,
                            const float* __restrict__ b1, const float* __restrict__ bout,
                            float* __restrict__ bias) {
    int i = blockIdx.x * 256 + threadIdx.x;
    if (i < 512)       bias[i] = bl[i] + b0[i] + b1[i];
    else if (i < 640)  bias[i] = bout[i - 512];
}

// ---------------- CSR pull gather: agg[node] = sum_{c in nbrs} hin[c] ----------------
__global__ void gather_kernel(const _Float16* __restrict__ hin, int ldin,
                              const int* __restrict__ rowptr, const int* __restrict__ col,
                              _Float16* __restrict__ dst, int ldd, int n) {
    int node = blockIdx.x * 4 + (threadIdx.x >> 6);
    int l = threadIdx.x & 63;
    if (node >= n) return;
    int s = rowptr[node], e = rowptr[node + 1];
    float a0 = 0.f, a1 = 0.f, a2 = 0.f, a3 = 0.f;
    for (int i = s; i < e; i++) {
        int c = col[i];
        half4_ v = *(const half4_*)(hin + (size_t)c * ldin + l * 4);
        a0 += (float)v[0]; a1 += (float)v[1]; a2 += (float)v[2]; a3 += (float)v[3];
    }
    half4_ o = { (_Float16)a0, (_Float16)a1, (_Float16)a2, (_Float16)a3 };
    *(half4_*)(dst + (size_t)node * ldd + l * 4) = o;
}

// ---------------- LayerNorm over H=256, wave per row ----------------
__global__ void ln_kernel(const _Float16* __restrict__ z,
                          const float* __restrict__ gamma,
                          const float* __restrict__ beta,
                          _Float16* __restrict__ dst, int ldd, int n) {
    int node = blockIdx.x * 4 + (threadIdx.x >> 6);
    int l = threadIdx.x & 63;
    if (node >= n) return;
    half4_ v4 = *(const half4_*)(z + (size_t)node * 256 + l * 4);
    float v0 = (float)v4[0], v1 = (float)v4[1], v2 = (float)v4[2], v3 = (float)v4[3];
    float s  = v0 + v1 + v2 + v3;
    float sq = v0 * v0 + v1 * v1 + v2 * v2 + v3 * v3;
    for (int off = 32; off > 0; off >>= 1) {
        s  += __shfl_xor(s, off, 64);
        sq += __shfl_xor(sq, off, 64);
    }
    float mu   = s * (1.0f / 256.0f);
    float var  = sq * (1.0f / 256.0f) - mu * mu;
    float rstd = rsqrtf(var + 1e-5f);
    float4_ g4 = *(const float4_*)(gamma + l * 4);
    float4_ b4 = *(const float4_*)(beta + l * 4);
    half4_ o;
    o[0] = (_Float16)((v0 - mu) * rstd * g4[0] + b4[0]);
    o[1] = (_Float16)((v1 - mu) * rstd * g4[1] + b4[1]);
    o[2] = (_Float16)((v2 - mu) * rstd * g4[2] + b4[2]);
    o[3] = (_Float16)((v3 - mu) * rstd * g4[3] + b4[3]);
    *(half4_*)(dst + (size_t)node * ldd + l * 4) = o;
}

// ---------------- GEMM: C = relu?(A @ B^T + bias), A[M,K] fp16, B[ncol,K] fp16 ----------------
// 128x128 tile, BK=32, 4 waves, 4x4 grid of 16x16x32 MFMA per wave.
// C output is fp16 (intermediate) or fp32 (final, d_out).
template <bool RELU, bool F32OUT>
__global__ __launch_bounds__(256) void gemm_bt(const _Float16* __restrict__ A, int lda,
                                               const _Float16* __restrict__ B, int ldb,
                                               const float* __restrict__ bias,
                                               void* __restrict__ Cv, int ldc,
                                               int K, int Mstore) {
    __shared__ _Float16 As[128 * 32];
    __shared__ _Float16 Bs[128 * 32];
    const int rowBase = blockIdx.x * 128;
    const int colBase = blockIdx.y * 128;
    const int tid  = threadIdx.x;
    const int lane = tid & 63;
    const int w    = tid >> 6;
    const int wm = w & 1, wn = w >> 1;
    const int quad = lane >> 4, mr = lane & 15;

    float4_ acc[4][4];
#pragma unroll
    for (int i = 0; i < 4; i++)
#pragma unroll
        for (int j = 0; j < 4; j++) { float4_ z4 = {0.f, 0.f, 0.f, 0.f}; acc[i][j] = z4; }

    // staging: 512 16B-chunks per tile; chunk c -> LDS byte c*16 == row-major [row][k] BK=32
    const int c0  = w * 64 + lane;        // 0..255
    const int rA0 = c0 >> 2;              // 0..63
    const int ko  = (c0 & 3) * 8;
    char* AsB = (char*)As;
    char* BsB = (char*)Bs;
    const _Float16* gA0 = A + (size_t)(rowBase + rA0) * lda + ko;
    const _Float16* gA1 = gA0 + (size_t)64 * lda;
    const _Float16* gB0 = B + (size_t)(colBase + rA0) * ldb + ko;
    const _Float16* gB1 = gB0 + (size_t)64 * ldb;

    for (int k0 = 0; k0 < K; k0 += 32) {
        uint4 vA0 = *(const uint4*)(gA0 + k0);
        uint4 vA1 = *(const uint4*)(gA1 + k0);
        uint4 vB0 = *(const uint4*)(gB0 + k0);
        uint4 vB1 = *(const uint4*)(gB1 + k0);
        *(uint4*)(AsB + c0 * 16)        = vA0;
        *(uint4*)(AsB + 4096 + c0 * 16) = vA1;
        *(uint4*)(BsB + c0 * 16)        = vB0;
        *(uint4*)(BsB + 4096 + c0 * 16) = vB1;
        __syncthreads();
        half8_ a[4], b[4];
#pragma unroll
        for (int im = 0; im < 4; im++)
            a[im] = *(const half8_*)(AsB + ((wm * 64 + im * 16 + mr) * 64 + quad * 16));
#pragma unroll
        for (int in = 0; in < 4; in++)
            b[in] = *(const half8_*)(BsB + ((wn * 64 + in * 16 + mr) * 64 + quad * 16));
#pragma unroll
        for (int im = 0; im < 4; im++)
#pragma unroll
            for (int in = 0; in < 4; in++)
                acc[im][in] = __builtin_amdgcn_mfma_f32_16x16x32_f16(a[im], b[in], acc[im][in], 0, 0, 0);
        __syncthreads();
    }

#pragma unroll
    for (int in = 0; in < 4; in++) {
        const int colg = colBase + wn * 64 + in * 16 + mr;
        const float bv = bias[colg];
#pragma unroll
        for (int im = 0; im < 4; im++) {
            float4_ c = acc[im][in];
#pragma unroll
            for (int r = 0; r < 4; r++) {
                int row = rowBase + wm * 64 + im * 16 + quad * 4 + r;
                if (row < Mstore) {
                    float v = c[r] + bv;
                    if (RELU) v = v > 0.f ? v : 0.f;
                    if (F32OUT) ((float*)Cv)[(size_t)row * ldc + colg] = v;
                    else        ((_Float16*)Cv)[(size_t)row * ldc + colg] = (_Float16)v;
                }
            }
        }
    }
}

extern "C" void kernel_launch(void* const* d_in, const int* in_sizes, int n_in,
                              void* d_out, int out_size, void* d_ws, size_t ws_size,
                              hipStream_t stream) {
    const float* x    = (const float*)d_in[0];
    const int*   e1   = (const int*)d_in[1];   // edge_r1: [0,E)=dst(e[0]), [E,2E)=src(e[1])
    const int*   e2   = (const int*)d_in[2];   // edge_r2
    const float* Wl   = (const float*)d_in[3];
    const float* bl   = (const float*)d_in[4];
    const float* W0   = (const float*)d_in[5];
    const float* b0   = (const float*)d_in[6];
    const float* W1   = (const float*)d_in[7];
    const float* b1   = (const float*)d_in[8];
    const float* gamma= (const float*)d_in[9];
    const float* beta = (const float*)d_in[10];
    const float* Wout = (const float*)d_in[11];
    const float* bout = (const float*)d_in[12];

    char* ws = (char*)d_ws;
    size_t off = 0;
    auto alloc = [&](size_t bytes) -> char* {
        char* p = ws + off;
        off = (off + bytes + 255) & ~(size_t)255;
        return p;
    };
    _Float16* A    = (_Float16*)alloc((size_t)NPAD * 768 * 2);  // [agg | h | x] fp16
    _Float16* z    = (_Float16*)alloc((size_t)NPAD * 256 * 2);
    _Float16* h2   = (_Float16*)alloc((size_t)NPAD * 256 * 2);
    _Float16* Wcat = (_Float16*)alloc((size_t)(2 * 256 * 768 + 128 * 256) * 2);
    float*    bias = (float*)alloc(640 * 4);
    int* cnt1 = (int*)alloc((size_t)N_NODES * 4);
    int* cnt2 = (int*)alloc((size_t)N_NODES * 4);
    int* rp1  = (int*)alloc((size_t)(N_NODES + 1) * 4);
    int* rp2  = (int*)alloc((size_t)(N_NODES + 1) * 4);
    int* cur1 = (int*)alloc((size_t)N_NODES * 4);
    int* cur2 = (int*)alloc((size_t)N_NODES * 4);
    int* col1 = (int*)alloc((size_t)N_EDGES * 4);
    int* col2 = (int*)alloc((size_t)N_EDGES * 4);

    hipMemsetAsync(cnt1, 0, (size_t)N_NODES * 4, stream);
    hipMemsetAsync(cnt2, 0, (size_t)N_NODES * 4, stream);

    const int eb = (N_EDGES + 255) / 256;
    count_kernel<<<eb, 256, 0, stream>>>(e1, cnt1, N_EDGES);
    count_kernel<<<eb, 256, 0, stream>>>(e2, cnt2, N_EDGES);
    scan_kernel<<<1, 1024, 0, stream>>>(cnt1, rp1, cur1, N_NODES);
    scan_kernel<<<1, 1024, 0, stream>>>(cnt2, rp2, cur2, N_NODES);
    fill_kernel<<<eb, 256, 0, stream>>>(e1, e1 + N_EDGES, cur1, col1, N_EDGES);
    fill_kernel<<<eb, 256, 0, stream>>>(e2, e2 + N_EDGES, cur2, col2, N_EDGES);

    copyx_kernel<<<(N_NODES * 64 + 255) / 256, 256, 0, stream>>>(x, A, N_NODES);
    pad_kernel<<<48, 256, 0, stream>>>(A, h2);
    wcat_kernel<<<(2 * 256 * 768 + 128 * 256 + 255) / 256, 256, 0, stream>>>(Wl, W0, W1, Wout, Wcat);
    bias_kernel<<<3, 256, 0, stream>>>(bl, b0, b1, bout, bias);

    const int nb4 = (N_NODES + 3) / 4;

    // ----- layer 1: weights idx 1, edges r2, h_in = x (A cols 512..767) -----
    gather_kernel<<<nb4, 256, 0, stream>>>(A + 512, 768, rp2, col2, A, 768, N_NODES);
    gemm_bt<true, false><<<dim3(391, 2), 256, 0, stream>>>(A, 768, Wcat + 196608, 768,
                                                           bias + 256, z, 256, 768, NPAD);
    ln_kernel<<<nb4, 256, 0, stream>>>(z, gamma + 256, beta + 256, A + 256, 768, N_NODES);

    // ----- layer 2: weights idx 0, edges r1, h_in = h1 (A cols 256..511) -----
    gather_kernel<<<nb4, 256, 0, stream>>>(A + 256, 768, rp1, col1, A, 768, N_NODES);
    gemm_bt<true, false><<<dim3(391, 2), 256, 0, stream>>>(A, 768, Wcat, 768,
                                                           bias, z, 256, 768, NPAD);
    ln_kernel<<<nb4, 256, 0, stream>>>(z, gamma, beta, h2, 256, N_NODES);

    // ----- output: out = h2 @ Wout^T + bout (fp32 to d_out) -----
    gemm_bt<false, true><<<dim3(391, 1), 256, 0, stream>>>(h2, 256, Wcat + 393216, 256,
                                                           bias + 512, d_out, 128, 256, N_NODES);
}

// Round 4
// 504.556 us; speedup vs baseline: 1.2943x; 1.2943x over previous
//
#include <hip/hip_runtime.h>
#include <stdint.h>

#define N_NODES 50000
#define N_EDGES 500000
#define NPAD    50048   // 391 * 128
#define NB      196     // ceil(50000/256)

typedef _Float16 half8_ __attribute__((ext_vector_type(8)));
typedef _Float16 half4_ __attribute__((ext_vector_type(4)));
typedef float    float4_ __attribute__((ext_vector_type(4)));

typedef uint32_t u32_g __attribute__((address_space(1)));
typedef uint32_t u32_s __attribute__((address_space(3)));

// async global->LDS, 16B/lane; LDS dest is wave-uniform base + lane*16 (m97 pattern).
__device__ __forceinline__ void gload16(const void* g, void* lds_wave_base) {
    __builtin_amdgcn_global_load_lds((const u32_g*)g, (u32_s*)lds_wave_base, 16, 0, 0);
}

// ---------------- CSR build ----------------
// grid (eb, 2): y selects edge set
__global__ void count_kernel(const int* __restrict__ e1, const int* __restrict__ e2,
                             int* __restrict__ cnt, int e, int n) {
    const int* dst = blockIdx.y ? e2 : e1;
    int* c = cnt + blockIdx.y * n;
    int i = blockIdx.x * 256 + threadIdx.x;
    if (i < e) atomicAdd(&c[dst[i]], 1);
}

// stage 1: per-256-chunk sums. grid (NB, 2)
__global__ void bsum_kernel(const int* __restrict__ cnt, int* __restrict__ bsums, int n) {
    const int* c = cnt + blockIdx.y * n;
    int i = blockIdx.x * 256 + threadIdx.x;
    int v = (i < n) ? c[i] : 0;
    for (int off = 32; off > 0; off >>= 1) v += __shfl_xor(v, off, 64);
    __shared__ int ws[4];
    if ((threadIdx.x & 63) == 0) ws[threadIdx.x >> 6] = v;
    __syncthreads();
    if (threadIdx.x == 0)
        bsums[blockIdx.y * 256 + blockIdx.x] = ws[0] + ws[1] + ws[2] + ws[3];
}

// stage 2: segmented scan of [2][256] block sums -> exclusive offsets (in place); writes rp[n].
__global__ void bscan_kernel(int* __restrict__ bsums, int* __restrict__ rp1,
                             int* __restrict__ rp2, int nb, int n) {
    __shared__ int sm[512];
    int t = threadIdx.x;
    int idx = t & 255;
    int v = (idx < nb) ? bsums[t] : 0;
    sm[t] = v;
    __syncthreads();
    for (int off = 1; off < 256; off <<= 1) {
        int x = sm[t];
        if (idx >= off) x += sm[t - off];
        __syncthreads();
        sm[t] = x;
        __syncthreads();
    }
    if (idx < nb) bsums[t] = (idx > 0) ? sm[t - 1] : 0;
    if (t == 255)  rp1[n] = sm[255];
    if (t == 511)  rp2[n] = sm[511];
}

// stage 3: block-local scan + offset. grid (NB, 2)
__global__ void bscatter_kernel(const int* __restrict__ cnt, const int* __restrict__ bsums,
                                int* __restrict__ rp, int* __restrict__ cur, int n) {
    const int* c = cnt + blockIdx.y * n;
    int* rpS  = rp  + blockIdx.y * (n + 1);
    int* curS = cur + blockIdx.y * n;
    __shared__ int sm[256];
    int t = threadIdx.x;
    int i = blockIdx.x * 256 + t;
    int v = (i < n) ? c[i] : 0;
    sm[t] = v;
    __syncthreads();
    for (int off = 1; off < 256; off <<= 1) {
        int x = sm[t];
        if (t >= off) x += sm[t - off];
        __syncthreads();
        sm[t] = x;
        __syncthreads();
    }
    int excl = sm[t] - v + bsums[blockIdx.y * 256 + blockIdx.x];
    if (i < n) { rpS[i] = excl; curS[i] = excl; }
}

// grid (eb, 2)
__global__ void fill_kernel(const int* __restrict__ e1, const int* __restrict__ e2,
                            int* __restrict__ cur, int* __restrict__ col, int e, int n) {
    const int* base = blockIdx.y ? e2 : e1;
    int* c  = cur + blockIdx.y * n;
    int* cl = col + blockIdx.y * e;
    int i = blockIdx.x * 256 + threadIdx.x;
    if (i < e) {
        int p = atomicAdd(&c[base[i]], 1);
        cl[p] = base[i + e];   // src = e[1]
    }
}

// ---------------- staging ----------------
// x (fp32) -> fp16 into A columns [256,512) and [512,768)
__global__ void copyx_kernel(const float* __restrict__ x, _Float16* __restrict__ A, int n) {
    int i = blockIdx.x * 256 + threadIdx.x;
    if (i >= n * 64) return;
    int nd = i >> 6, l = i & 63;
    float4_ v = *(const float4_*)(x + (size_t)nd * 256 + l * 4);
    half4_ h;
    h[0] = (_Float16)v[0]; h[1] = (_Float16)v[1];
    h[2] = (_Float16)v[2]; h[3] = (_Float16)v[3];
    *(half4_*)(A + (size_t)nd * 768 + 256 + l * 4) = h;
    *(half4_*)(A + (size_t)nd * 768 + 512 + l * 4) = h;
}

// zero the padded rows of A (768 wide) and h2 (256 wide)
__global__ void pad_kernel(_Float16* __restrict__ A, _Float16* __restrict__ h2) {
    int i = blockIdx.x * 256 + threadIdx.x;
    half4_ z = {(_Float16)0.f, (_Float16)0.f, (_Float16)0.f, (_Float16)0.f};
    if (i < 9216) {
        *(half4_*)(A + (size_t)N_NODES * 768 + (size_t)i * 4) = z;
    } else if (i < 12288) {
        *(half4_*)(h2 + (size_t)N_NODES * 256 + (size_t)(i - 9216) * 4) = z;
    }
}

// Wcat[l][j][0:768] = [Wl[l][j] | W0[l][j] | W1[l][j]] as fp16; then Wout as fp16.
__global__ void wcat_kernel(const float* __restrict__ Wl, const float* __restrict__ W0,
                            const float* __restrict__ W1, const float* __restrict__ Wout,
                            _Float16* __restrict__ Wcat) {
    int i = blockIdx.x * 256 + threadIdx.x;
    if (i < 2 * 256 * 768) {
        int l = i / (256 * 768);
        int r = i % (256 * 768);
        int j = r / 768, k = r % 768;
        const float* s = (k < 256) ? Wl : (k < 512 ? W0 : W1);
        Wcat[i] = (_Float16)s[l * 65536 + j * 256 + (k & 255)];
    } else if (i < 2 * 256 * 768 + 128 * 256) {
        int r = i - 2 * 256 * 768;
        Wcat[i] = (_Float16)Wout[r];
    }
}

__global__ void bias_kernel(const float* __restrict__ bl, const float* __restrict__ b0,
                            const float* __restrict__ b1, const float* __restrict__ bout,
                            float* __restrict__ bias) {
    int i = blockIdx.x * 256 + threadIdx.x;
    if (i < 512)       bias[i] = bl[i] + b0[i] + b1[i];
    else if (i < 640)  bias[i] = bout[i - 512];
}

// ---------------- CSR pull gather ----------------
__global__ void gather_kernel(const _Float16* __restrict__ hin, int ldin,
                              const int* __restrict__ rowptr, const int* __restrict__ col,
                              _Float16* __restrict__ dst, int ldd, int n) {
    int node = blockIdx.x * 4 + (threadIdx.x >> 6);
    int l = threadIdx.x & 63;
    if (node >= n) return;
    int s = rowptr[node], e = rowptr[node + 1];
    float a0 = 0.f, a1 = 0.f, a2 = 0.f, a3 = 0.f;
    for (int i = s; i < e; i++) {
        int c = col[i];
        half4_ v = *(const half4_*)(hin + (size_t)c * ldin + l * 4);
        a0 += (float)v[0]; a1 += (float)v[1]; a2 += (float)v[2]; a3 += (float)v[3];
    }
    half4_ o = { (_Float16)a0, (_Float16)a1, (_Float16)a2, (_Float16)a3 };
    *(half4_*)(dst + (size_t)node * ldd + l * 4) = o;
}

// ---------------- LayerNorm over H=256, wave per row ----------------
__global__ void ln_kernel(const _Float16* __restrict__ z,
                          const float* __restrict__ gamma,
                          const float* __restrict__ beta,
                          _Float16* __restrict__ dst, int ldd, int n) {
    int node = blockIdx.x * 4 + (threadIdx.x >> 6);
    int l = threadIdx.x & 63;
    if (node >= n) return;
    half4_ v4 = *(const half4_*)(z + (size_t)node * 256 + l * 4);
    float v0 = (float)v4[0], v1 = (float)v4[1], v2 = (float)v4[2], v3 = (float)v4[3];
    float s  = v0 + v1 + v2 + v3;
    float sq = v0 * v0 + v1 * v1 + v2 * v2 + v3 * v3;
    for (int off = 32; off > 0; off >>= 1) {
        s  += __shfl_xor(s, off, 64);
        sq += __shfl_xor(sq, off, 64);
    }
    float mu   = s * (1.0f / 256.0f);
    float var  = sq * (1.0f / 256.0f) - mu * mu;
    float rstd = rsqrtf(var + 1e-5f);
    float4_ g4 = *(const float4_*)(gamma + l * 4);
    float4_ b4 = *(const float4_*)(beta + l * 4);
    half4_ o;
    o[0] = (_Float16)((v0 - mu) * rstd * g4[0] + b4[0]);
    o[1] = (_Float16)((v1 - mu) * rstd * g4[1] + b4[1]);
    o[2] = (_Float16)((v2 - mu) * rstd * g4[2] + b4[2]);
    o[3] = (_Float16)((v3 - mu) * rstd * g4[3] + b4[3]);
    *(half4_*)(dst + (size_t)node * ldd + l * 4) = o;
}

// ---------------- GEMM: C = relu?(A @ B^T + bias) ----------------
// 128x128 tile, BK=32, 4 waves, 4x4 of 16x16x32 f16 MFMA; global_load_lds staging.
template <bool RELU, bool F32OUT>
__global__ __launch_bounds__(256) void gemm_bt(const _Float16* __restrict__ A, int lda,
                                               const _Float16* __restrict__ B, int ldb,
                                               const float* __restrict__ bias,
                                               void* __restrict__ Cv, int ldc,
                                               int K, int Mstore) {
    __shared__ _Float16 As[128 * 32];
    __shared__ _Float16 Bs[128 * 32];
    const int rowBase = blockIdx.x * 128;
    const int colBase = blockIdx.y * 128;
    const int tid  = threadIdx.x;
    const int lane = tid & 63;
    const int w    = tid >> 6;
    const int wm = w & 1, wn = w >> 1;
    const int quad = lane >> 4, mr = lane & 15;

    float4_ acc[4][4];
#pragma unroll
    for (int i = 0; i < 4; i++)
#pragma unroll
        for (int j = 0; j < 4; j++) { float4_ z4 = {0.f, 0.f, 0.f, 0.f}; acc[i][j] = z4; }

    const int c0  = w * 64 + lane;        // 0..255
    const int rA0 = c0 >> 2;              // 0..63
    const int ko  = (c0 & 3) * 8;
    char* AsB = (char*)As;
    char* BsB = (char*)Bs;
    void* lA0 = AsB + w * 1024;
    void* lA1 = AsB + 4096 + w * 1024;
    void* lB0 = BsB + w * 1024;
    void* lB1 = BsB + 4096 + w * 1024;
    const _Float16* gA0 = A + (size_t)(rowBase + rA0) * lda + ko;
    const _Float16* gA1 = gA0 + (size_t)64 * lda;
    const _Float16* gB0 = B + (size_t)(colBase + rA0) * ldb + ko;
    const _Float16* gB1 = gB0 + (size_t)64 * ldb;

    for (int k0 = 0; k0 < K; k0 += 32) {
        gload16(gA0 + k0, lA0);
        gload16(gA1 + k0, lA1);
        gload16(gB0 + k0, lB0);
        gload16(gB1 + k0, lB1);
        __syncthreads();
        half8_ a[4], b[4];
#pragma unroll
        for (int im = 0; im < 4; im++)
            a[im] = *(const half8_*)(AsB + ((wm * 64 + im * 16 + mr) * 64 + quad * 16));
#pragma unroll
        for (int in = 0; in < 4; in++)
            b[in] = *(const half8_*)(BsB + ((wn * 64 + in * 16 + mr) * 64 + quad * 16));
#pragma unroll
        for (int im = 0; im < 4; im++)
#pragma unroll
            for (int in = 0; in < 4; in++)
                acc[im][in] = __builtin_amdgcn_mfma_f32_16x16x32_f16(a[im], b[in], acc[im][in], 0, 0, 0);
        __syncthreads();
    }

#pragma unroll
    for (int in = 0; in < 4; in++) {
        const int colg = colBase + wn * 64 + in * 16 + mr;
        const float bv = bias[colg];
#pragma unroll
        for (int im = 0; im < 4; im++) {
            float4_ c = acc[im][in];
#pragma unroll
            for (int r = 0; r < 4; r++) {
                int row = rowBase + wm * 64 + im * 16 + quad * 4 + r;
                if (row < Mstore) {
                    float v = c[r] + bv;
                    if (RELU) v = v > 0.f ? v : 0.f;
                    if (F32OUT) ((float*)Cv)[(size_t)row * ldc + colg] = v;
                    else        ((_Float16*)Cv)[(size_t)row * ldc + colg] = (_Float16)v;
                }
            }
        }
    }
}

extern "C" void kernel_launch(void* const* d_in, const int* in_sizes, int n_in,
                              void* d_out, int out_size, void* d_ws, size_t ws_size,
                              hipStream_t stream) {
    const float* x    = (const float*)d_in[0];
    const int*   e1   = (const int*)d_in[1];
    const int*   e2   = (const int*)d_in[2];
    const float* Wl   = (const float*)d_in[3];
    const float* bl   = (const float*)d_in[4];
    const float* W0   = (const float*)d_in[5];
    const float* b0   = (const float*)d_in[6];
    const float* W1   = (const float*)d_in[7];
    const float* b1   = (const float*)d_in[8];
    const float* gamma= (const float*)d_in[9];
    const float* beta = (const float*)d_in[10];
    const float* Wout = (const float*)d_in[11];
    const float* bout = (const float*)d_in[12];

    char* ws = (char*)d_ws;
    size_t off = 0;
    auto alloc = [&](size_t bytes) -> char* {
        char* p = ws + off;
        off = (off + bytes + 255) & ~(size_t)255;
        return p;
    };
    _Float16* A    = (_Float16*)alloc((size_t)NPAD * 768 * 2);
    _Float16* z    = (_Float16*)alloc((size_t)NPAD * 256 * 2);
    _Float16* h2   = (_Float16*)alloc((size_t)NPAD * 256 * 2);
    _Float16* Wcat = (_Float16*)alloc((size_t)(2 * 256 * 768 + 128 * 256) * 2);
    float*    bias = (float*)alloc(640 * 4);
    int* cnt   = (int*)alloc((size_t)2 * N_NODES * 4);
    int* rp    = (int*)alloc((size_t)2 * (N_NODES + 1) * 4);
    int* cur   = (int*)alloc((size_t)2 * N_NODES * 4);
    int* col   = (int*)alloc((size_t)2 * N_EDGES * 4);
    int* bsums = (int*)alloc(512 * 4);

    int* rp1 = rp, *rp2 = rp + (N_NODES + 1);
    int* col1 = col, *col2 = col + N_EDGES;

    hipMemsetAsync(cnt, 0, (size_t)2 * N_NODES * 4, stream);

    const int eb = (N_EDGES + 255) / 256;
    count_kernel<<<dim3(eb, 2), 256, 0, stream>>>(e1, e2, cnt, N_EDGES, N_NODES);
    bsum_kernel<<<dim3(NB, 2), 256, 0, stream>>>(cnt, bsums, N_NODES);
    bscan_kernel<<<1, 512, 0, stream>>>(bsums, rp1, rp2, NB, N_NODES);
    bscatter_kernel<<<dim3(NB, 2), 256, 0, stream>>>(cnt, bsums, rp, cur, N_NODES);
    fill_kernel<<<dim3(eb, 2), 256, 0, stream>>>(e1, e2, cur, col, N_EDGES, N_NODES);

    copyx_kernel<<<(N_NODES * 64 + 255) / 256, 256, 0, stream>>>(x, A, N_NODES);
    pad_kernel<<<48, 256, 0, stream>>>(A, h2);
    wcat_kernel<<<(2 * 256 * 768 + 128 * 256 + 255) / 256, 256, 0, stream>>>(Wl, W0, W1, Wout, Wcat);
    bias_kernel<<<3, 256, 0, stream>>>(bl, b0, b1, bout, bias);

    const int nb4 = (N_NODES + 3) / 4;

    // ----- layer 1: weights idx 1, edges r2, h_in = x (A cols 512..767) -----
    gather_kernel<<<nb4, 256, 0, stream>>>(A + 512, 768, rp2, col2, A, 768, N_NODES);
    gemm_bt<true, false><<<dim3(391, 2), 256, 0, stream>>>(A, 768, Wcat + 196608, 768,
                                                           bias + 256, z, 256, 768, NPAD);
    ln_kernel<<<nb4, 256, 0, stream>>>(z, gamma + 256, beta + 256, A + 256, 768, N_NODES);

    // ----- layer 2: weights idx 0, edges r1, h_in = h1 (A cols 256..511) -----
    gather_kernel<<<nb4, 256, 0, stream>>>(A + 256, 768, rp1, col1, A, 768, N_NODES);
    gemm_bt<true, false><<<dim3(391, 2), 256, 0, stream>>>(A, 768, Wcat, 768,
                                                           bias, z, 256, 768, NPAD);
    ln_kernel<<<nb4, 256, 0, stream>>>(z, gamma, beta, h2, 256, N_NODES);

    // ----- output: out = h2 @ Wout^T + bout (fp32 to d_out) -----
    gemm_bt<false, true><<<dim3(391, 1), 256, 0, stream>>>(h2, 256, Wcat + 393216, 256,
                                                           bias + 512, d_out, 128, 256, N_NODES);
}

// Round 5
// 446.333 us; speedup vs baseline: 1.4631x; 1.1304x over previous
//
#include <hip/hip_runtime.h>
#include <stdint.h>

#define N_NODES 50000
#define N_EDGES 500000
#define NPAD    50048   // 391 * 128
#define NB      196     // ceil(50000/256)
#define EPS     1e-5f

typedef _Float16 half8_ __attribute__((ext_vector_type(8)));
typedef _Float16 half4_ __attribute__((ext_vector_type(4)));
typedef float    float4_ __attribute__((ext_vector_type(4)));

typedef uint32_t u32_g __attribute__((address_space(1)));
typedef uint32_t u32_s __attribute__((address_space(3)));

// async global->LDS, 16B/lane; LDS dest is wave-uniform base + lane*16 (m97 pattern).
__device__ __forceinline__ void gload16(const void* g, void* lds_wave_base) {
    __builtin_amdgcn_global_load_lds((const u32_g*)g, (u32_s*)lds_wave_base, 16, 0, 0);
}

// ---------------- CSR build ----------------
__global__ void count_kernel(const int* __restrict__ e1, const int* __restrict__ e2,
                             int* __restrict__ cnt, int e, int n) {
    const int* dst = blockIdx.y ? e2 : e1;
    int* c = cnt + blockIdx.y * n;
    int i = blockIdx.x * 256 + threadIdx.x;
    if (i < e) atomicAdd(&c[dst[i]], 1);
}

__global__ void bsum_kernel(const int* __restrict__ cnt, int* __restrict__ bsums, int n) {
    const int* c = cnt + blockIdx.y * n;
    int i = blockIdx.x * 256 + threadIdx.x;
    int v = (i < n) ? c[i] : 0;
    for (int off = 32; off > 0; off >>= 1) v += __shfl_xor(v, off, 64);
    __shared__ int ws[4];
    if ((threadIdx.x & 63) == 0) ws[threadIdx.x >> 6] = v;
    __syncthreads();
    if (threadIdx.x == 0)
        bsums[blockIdx.y * 256 + blockIdx.x] = ws[0] + ws[1] + ws[2] + ws[3];
}

__global__ void bscan_kernel(int* __restrict__ bsums, int* __restrict__ rp1,
                             int* __restrict__ rp2, int nb, int n) {
    __shared__ int sm[512];
    int t = threadIdx.x;
    int idx = t & 255;
    int v = (idx < nb) ? bsums[t] : 0;
    sm[t] = v;
    __syncthreads();
    for (int off = 1; off < 256; off <<= 1) {
        int x = sm[t];
        if (idx >= off) x += sm[t - off];
        __syncthreads();
        sm[t] = x;
        __syncthreads();
    }
    if (idx < nb) bsums[t] = (idx > 0) ? sm[t - 1] : 0;
    if (t == 255)  rp1[n] = sm[255];
    if (t == 511)  rp2[n] = sm[511];
}

__global__ void bscatter_kernel(const int* __restrict__ cnt, const int* __restrict__ bsums,
                                int* __restrict__ rp, int* __restrict__ cur, int n) {
    const int* c = cnt + blockIdx.y * n;
    int* rpS  = rp  + blockIdx.y * (n + 1);
    int* curS = cur + blockIdx.y * n;
    __shared__ int sm[256];
    int t = threadIdx.x;
    int i = blockIdx.x * 256 + t;
    int v = (i < n) ? c[i] : 0;
    sm[t] = v;
    __syncthreads();
    for (int off = 1; off < 256; off <<= 1) {
        int x = sm[t];
        if (t >= off) x += sm[t - off];
        __syncthreads();
        sm[t] = x;
        __syncthreads();
    }
    int excl = sm[t] - v + bsums[blockIdx.y * 256 + blockIdx.x];
    if (i < n) { rpS[i] = excl; curS[i] = excl; }
}

__global__ void fill_kernel(const int* __restrict__ e1, const int* __restrict__ e2,
                            int* __restrict__ cur, int* __restrict__ col, int e, int n) {
    const int* base = blockIdx.y ? e2 : e1;
    int* c  = cur + blockIdx.y * n;
    int* cl = col + blockIdx.y * e;
    int i = blockIdx.x * 256 + threadIdx.x;
    if (i < e) {
        int p = atomicAdd(&c[base[i]], 1);
        cl[p] = base[i + e];   // src = e[1]
    }
}

// ---------------- staging ----------------
// x (fp32, [n][256]) -> fp16 xh (same layout)
__global__ void copyx_kernel(const float* __restrict__ x, _Float16* __restrict__ xh, int n) {
    int i = blockIdx.x * 256 + threadIdx.x;
    if (i >= n * 64) return;
    float4_ v = ((const float4_*)x)[i];
    half4_ h;
    h[0] = (_Float16)v[0]; h[1] = (_Float16)v[1];
    h[2] = (_Float16)v[2]; h[3] = (_Float16)v[3];
    ((half4_*)xh)[i] = h;
}

// zero pad rows [N_NODES, NPAD) of 4 ld-256 buffers
__global__ void pad_kernel(_Float16* __restrict__ a, _Float16* __restrict__ b,
                           _Float16* __restrict__ c, _Float16* __restrict__ d) {
    int i = blockIdx.x * 256 + threadIdx.x;          // 0..12287 (48 blocks)
    int buf = i / 3072, j = i % 3072;                // 3072 half4 per buffer tail
    _Float16* p = (buf == 0) ? a : (buf == 1) ? b : (buf == 2) ? c : d;
    half4_ z = {(_Float16)0.f, (_Float16)0.f, (_Float16)0.f, (_Float16)0.f};
    *(half4_*)(p + (size_t)N_NODES * 256 + (size_t)j * 4) = z;
}

// Wcat[l][j][0:768] = [Wl[l][j] | W0[l][j] | W1[l][j]] fp16; then Wout [128][256] fp16.
__global__ void wcat_kernel(const float* __restrict__ Wl, const float* __restrict__ W0,
                            const float* __restrict__ W1, const float* __restrict__ Wout,
                            _Float16* __restrict__ Wcat) {
    int i = blockIdx.x * 256 + threadIdx.x;
    if (i < 2 * 256 * 768) {
        int l = i / (256 * 768);
        int r = i % (256 * 768);
        int j = r / 768, k = r % 768;
        const float* s = (k < 256) ? Wl : (k < 512 ? W0 : W1);
        Wcat[i] = (_Float16)s[l * 65536 + j * 256 + (k & 255)];
    } else if (i < 2 * 256 * 768 + 128 * 256) {
        int r = i - 2 * 256 * 768;
        Wcat[i] = (_Float16)Wout[r];
    }
}

__global__ void bias_kernel(const float* __restrict__ bl, const float* __restrict__ b0,
                            const float* __restrict__ b1, const float* __restrict__ bout,
                            float* __restrict__ bias) {
    int i = blockIdx.x * 256 + threadIdx.x;
    if (i < 512)       bias[i] = bl[i] + b0[i] + b1[i];
    else if (i < 640)  bias[i] = bout[i - 512];
}

// ---------------- CSR pull gather: agg[node] = sum hin[col[i]] (ld 256 both) -------------
__global__ void gather_kernel(const _Float16* __restrict__ hin,
                              const int* __restrict__ rowptr, const int* __restrict__ col,
                              _Float16* __restrict__ dst, int n) {
    int node = blockIdx.x * 4 + (threadIdx.x >> 6);
    int l = threadIdx.x & 63;
    if (node >= n) return;
    int s = rowptr[node], e = rowptr[node + 1];
    float a0 = 0.f, a1 = 0.f, a2 = 0.f, a3 = 0.f;
    for (int i = s; i < e; i++) {
        int c = col[i];
        half4_ v = *(const half4_*)(hin + (size_t)c * 256 + l * 4);
        a0 += (float)v[0]; a1 += (float)v[1]; a2 += (float)v[2]; a3 += (float)v[3];
    }
    half4_ o = { (_Float16)a0, (_Float16)a1, (_Float16)a2, (_Float16)a3 };
    *(half4_*)(dst + (size_t)node * 256 + l * 4) = o;
}

// ---------------- fused layer GEMM: H = LN(relu([agg|h|x] @ W^T + bias)) ----------------
// 512 threads, tile 128 rows x 256 cols, K=768, BK=64, swizzled LDS, LDS-transpose store.
__global__ __launch_bounds__(512) void gemm_ln(const _Float16* __restrict__ agg,
                                               const _Float16* __restrict__ hsrc,
                                               const _Float16* __restrict__ xh,
                                               const _Float16* __restrict__ Bw,  // [256][768]
                                               const float* __restrict__ bias,   // [256]
                                               const float* __restrict__ gamma,
                                               const float* __restrict__ beta,
                                               _Float16* __restrict__ H) {       // [NPAD][256]
    __shared__ __align__(16) char smem[49152];   // As 16K | Bs 32K
    char* AsB = smem;
    char* BsB = smem + 16384;
    const int rowBase = blockIdx.x * 128;
    const int tid  = threadIdx.x;
    const int lane = tid & 63;
    const int w    = tid >> 6;          // 0..7
    const int wm = w & 1, wn = w >> 1;  // row group (0..1), col group (0..3)
    const int quad = lane >> 4, mr = lane & 15;
    const int x7 = mr & 7;              // frag-read swizzle key (row&7 == mr&7)

    float4_ acc[4][4];
#pragma unroll
    for (int i = 0; i < 4; i++)
#pragma unroll
        for (int j = 0; j < 4; j++) { float4_ z4 = {0.f, 0.f, 0.f, 0.f}; acc[i][j] = z4; }

    // staging chunk geometry: chunk c -> LDS byte c*16; row = c>>3, kslot = c&7.
    // LDS slot (row, kslot) receives GLOBAL chunk (row, kslot ^ (row&7))  [bank swizzle]
    int cA0 = w * 64 + lane, cA1 = cA0 + 512;
    int rA0 = cA0 >> 3, rA1 = cA1 >> 3;
    size_t offA0 = (size_t)(rowBase + rA0) * 256 + (((cA0 & 7) ^ (rA0 & 7)) * 8);
    size_t offA1 = (size_t)(rowBase + rA1) * 256 + (((cA1 & 7) ^ (rA1 & 7)) * 8);
    size_t offB[4];
#pragma unroll
    for (int j = 0; j < 4; j++) {
        int c = j * 512 + w * 64 + lane;
        int r = c >> 3;
        offB[j] = (size_t)r * 768 + (((c & 7) ^ (r & 7)) * 8);
    }
    void* lA0 = AsB + w * 1024;
    void* lA1 = AsB + 8192 + w * 1024;

    for (int k0 = 0; k0 < 768; k0 += 64) {
        const _Float16* src = (k0 < 256) ? agg : (k0 < 512) ? hsrc : xh;
        const int kloc = k0 & 255;
        gload16(src + offA0 + kloc, lA0);
        gload16(src + offA1 + kloc, lA1);
        gload16(Bw + offB[0] + k0, BsB + w * 1024);
        gload16(Bw + offB[1] + k0, BsB + 8192 + w * 1024);
        gload16(Bw + offB[2] + k0, BsB + 16384 + w * 1024);
        gload16(Bw + offB[3] + k0, BsB + 24576 + w * 1024);
        __syncthreads();
#pragma unroll
        for (int s = 0; s < 2; s++) {
            half8_ a[4], b[4];
#pragma unroll
            for (int im = 0; im < 4; im++) {
                int row = wm * 64 + im * 16 + mr;
                a[im] = *(const half8_*)(AsB + row * 128 + (((s * 4 + quad) ^ x7) * 16));
            }
#pragma unroll
            for (int in = 0; in < 4; in++) {
                int row = wn * 64 + in * 16 + mr;
                b[in] = *(const half8_*)(BsB + row * 128 + (((s * 4 + quad) ^ x7) * 16));
            }
#pragma unroll
            for (int im = 0; im < 4; im++)
#pragma unroll
                for (int in = 0; in < 4; in++)
                    acc[im][in] = __builtin_amdgcn_mfma_f32_16x16x32_f16(a[im], b[in], acc[im][in], 0, 0, 0);
        }
        __syncthreads();
    }

    // ---- epilogue: bias + relu + LayerNorm + transpose-store ----
    float bv[4], gv[4], bev[4];
#pragma unroll
    for (int in = 0; in < 4; in++) {
        int colg = wn * 64 + in * 16 + mr;
        bv[in]  = bias[colg];
        gv[in]  = gamma[colg];
        bev[in] = beta[colg];
    }
    float* lnbuf   = (float*)AsB;            // [4 wn][128 row][2]
    float* lnstats = (float*)(AsB + 4096);   // [128][2] {mu, rstd}

#pragma unroll
    for (int im = 0; im < 4; im++)
#pragma unroll
        for (int r = 0; r < 4; r++) {
            float s = 0.f, sq = 0.f;
#pragma unroll
            for (int in = 0; in < 4; in++) {
                float v = acc[im][in][r] + bv[in];
                v = v > 0.f ? v : 0.f;
                s += v; sq += v * v;
            }
            s  += __shfl_xor(s, 1, 64);  sq += __shfl_xor(sq, 1, 64);
            s  += __shfl_xor(s, 2, 64);  sq += __shfl_xor(sq, 2, 64);
            s  += __shfl_xor(s, 4, 64);  sq += __shfl_xor(sq, 4, 64);
            s  += __shfl_xor(s, 8, 64);  sq += __shfl_xor(sq, 8, 64);
            if (mr == 0) {
                int rl = wm * 64 + im * 16 + quad * 4 + r;
                lnbuf[(wn * 128 + rl) * 2]     = s;
                lnbuf[(wn * 128 + rl) * 2 + 1] = sq;
            }
        }
    __syncthreads();
    if (tid < 128) {
        float s  = lnbuf[tid * 2]           + lnbuf[(128 + tid) * 2]
                 + lnbuf[(256 + tid) * 2]   + lnbuf[(384 + tid) * 2];
        float sq = lnbuf[tid * 2 + 1]       + lnbuf[(128 + tid) * 2 + 1]
                 + lnbuf[(256 + tid) * 2 + 1] + lnbuf[(384 + tid) * 2 + 1];
        float mu  = s * (1.0f / 256.0f);
        float var = sq * (1.0f / 256.0f) - mu * mu;
        lnstats[tid * 2]     = mu;
        lnstats[tid * 2 + 1] = rsqrtf(var + EPS);
    }
    __syncthreads();

    _Float16* BsH = (_Float16*)BsB;          // transpose buffer: [64 rows][256 cols]
#pragma unroll
    for (int p = 0; p < 2; p++) {
        if (wm == p) {
#pragma unroll
            for (int im = 0; im < 4; im++)
#pragma unroll
                for (int r = 0; r < 4; r++) {
                    int rl = im * 16 + quad * 4 + r;           // 0..63 within group
                    float mu = lnstats[(p * 64 + rl) * 2];
                    float rs = lnstats[(p * 64 + rl) * 2 + 1];
#pragma unroll
                    for (int in = 0; in < 4; in++) {
                        float v = acc[im][in][r] + bv[in];
                        v = v > 0.f ? v : 0.f;
                        BsH[rl * 256 + wn * 64 + in * 16 + mr] =
                            (_Float16)((v - mu) * rs * gv[in] + bev[in]);
                    }
                }
        }
        __syncthreads();
        // 64 rows * 512B = 2048 chunks of 16B; 512 threads * 4
#pragma unroll
        for (int i = 0; i < 4; i++) {
            int c = i * 512 + tid;
            int row = c >> 5, ch = c & 31;
            half8_ v = *(const half8_*)(BsB + c * 16);
            *(half8_*)(H + (size_t)(rowBase + p * 64 + row) * 256 + ch * 8) = v;
        }
        __syncthreads();
    }
}

// ---------------- final GEMM: d_out = h2 @ Wout^T + bout (fp32) ----------------
__global__ __launch_bounds__(256) void gemm_bt(const _Float16* __restrict__ A, int lda,
                                               const _Float16* __restrict__ B, int ldb,
                                               const float* __restrict__ bias,
                                               float* __restrict__ C, int ldc,
                                               int K, int Mstore) {
    __shared__ _Float16 As[128 * 32];
    __shared__ _Float16 Bs[128 * 32];
    const int rowBase = blockIdx.x * 128;
    const int colBase = blockIdx.y * 128;
    const int tid  = threadIdx.x;
    const int lane = tid & 63;
    const int w    = tid >> 6;
    const int wm = w & 1, wn = w >> 1;
    const int quad = lane >> 4, mr = lane & 15;

    float4_ acc[4][4];
#pragma unroll
    for (int i = 0; i < 4; i++)
#pragma unroll
        for (int j = 0; j < 4; j++) { float4_ z4 = {0.f, 0.f, 0.f, 0.f}; acc[i][j] = z4; }

    const int c0  = w * 64 + lane;
    const int rA0 = c0 >> 2;
    const int ko  = (c0 & 3) * 8;
    char* AsB = (char*)As;
    char* BsB = (char*)Bs;
    void* lA0 = AsB + w * 1024;
    void* lA1 = AsB + 4096 + w * 1024;
    void* lB0 = BsB + w * 1024;
    void* lB1 = BsB + 4096 + w * 1024;
    const _Float16* gA0 = A + (size_t)(rowBase + rA0) * lda + ko;
    const _Float16* gA1 = gA0 + (size_t)64 * lda;
    const _Float16* gB0 = B + (size_t)(colBase + rA0) * ldb + ko;
    const _Float16* gB1 = gB0 + (size_t)64 * ldb;

    for (int k0 = 0; k0 < K; k0 += 32) {
        gload16(gA0 + k0, lA0);
        gload16(gA1 + k0, lA1);
        gload16(gB0 + k0, lB0);
        gload16(gB1 + k0, lB1);
        __syncthreads();
        half8_ a[4], b[4];
#pragma unroll
        for (int im = 0; im < 4; im++)
            a[im] = *(const half8_*)(AsB + ((wm * 64 + im * 16 + mr) * 64 + quad * 16));
#pragma unroll
        for (int in = 0; in < 4; in++)
            b[in] = *(const half8_*)(BsB + ((wn * 64 + in * 16 + mr) * 64 + quad * 16));
#pragma unroll
        for (int im = 0; im < 4; im++)
#pragma unroll
            for (int in = 0; in < 4; in++)
                acc[im][in] = __builtin_amdgcn_mfma_f32_16x16x32_f16(a[im], b[in], acc[im][in], 0, 0, 0);
        __syncthreads();
    }

#pragma unroll
    for (int in = 0; in < 4; in++) {
        const int colg = colBase + wn * 64 + in * 16 + mr;
        const float bv = bias[colg];
#pragma unroll
        for (int im = 0; im < 4; im++) {
            float4_ c = acc[im][in];
#pragma unroll
            for (int r = 0; r < 4; r++) {
                int row = rowBase + wm * 64 + im * 16 + quad * 4 + r;
                if (row < Mstore) C[(size_t)row * ldc + colg] = c[r] + bv;
            }
        }
    }
}

extern "C" void kernel_launch(void* const* d_in, const int* in_sizes, int n_in,
                              void* d_out, int out_size, void* d_ws, size_t ws_size,
                              hipStream_t stream) {
    const float* x    = (const float*)d_in[0];
    const int*   e1   = (const int*)d_in[1];
    const int*   e2   = (const int*)d_in[2];
    const float* Wl   = (const float*)d_in[3];
    const float* bl   = (const float*)d_in[4];
    const float* W0   = (const float*)d_in[5];
    const float* b0   = (const float*)d_in[6];
    const float* W1   = (const float*)d_in[7];
    const float* b1   = (const float*)d_in[8];
    const float* gamma= (const float*)d_in[9];
    const float* beta = (const float*)d_in[10];
    const float* Wout = (const float*)d_in[11];
    const float* bout = (const float*)d_in[12];

    char* ws = (char*)d_ws;
    size_t off = 0;
    auto alloc = [&](size_t bytes) -> char* {
        char* p = ws + off;
        off = (off + bytes + 255) & ~(size_t)255;
        return p;
    };
    _Float16* xh   = (_Float16*)alloc((size_t)NPAD * 256 * 2);
    _Float16* aggb = (_Float16*)alloc((size_t)NPAD * 256 * 2);
    _Float16* h1   = (_Float16*)alloc((size_t)NPAD * 256 * 2);
    _Float16* h2   = (_Float16*)alloc((size_t)NPAD * 256 * 2);
    _Float16* Wcat = (_Float16*)alloc((size_t)(2 * 256 * 768 + 128 * 256) * 2);
    float*    bias = (float*)alloc(640 * 4);
    int* cnt   = (int*)alloc((size_t)2 * N_NODES * 4);
    int* rp    = (int*)alloc((size_t)2 * (N_NODES + 1) * 4);
    int* cur   = (int*)alloc((size_t)2 * N_NODES * 4);
    int* col   = (int*)alloc((size_t)2 * N_EDGES * 4);
    int* bsums = (int*)alloc(512 * 4);

    int* rp1 = rp, *rp2 = rp + (N_NODES + 1);
    int* col1 = col, *col2 = col + N_EDGES;

    hipMemsetAsync(cnt, 0, (size_t)2 * N_NODES * 4, stream);

    const int eb = (N_EDGES + 255) / 256;
    count_kernel<<<dim3(eb, 2), 256, 0, stream>>>(e1, e2, cnt, N_EDGES, N_NODES);
    bsum_kernel<<<dim3(NB, 2), 256, 0, stream>>>(cnt, bsums, N_NODES);
    bscan_kernel<<<1, 512, 0, stream>>>(bsums, rp1, rp2, NB, N_NODES);
    bscatter_kernel<<<dim3(NB, 2), 256, 0, stream>>>(cnt, bsums, rp, cur, N_NODES);
    fill_kernel<<<dim3(eb, 2), 256, 0, stream>>>(e1, e2, cur, col, N_EDGES, N_NODES);

    copyx_kernel<<<12500, 256, 0, stream>>>(x, xh, N_NODES);
    pad_kernel<<<48, 256, 0, stream>>>(xh, aggb, h1, h2);
    wcat_kernel<<<(2 * 256 * 768 + 128 * 256 + 255) / 256, 256, 0, stream>>>(Wl, W0, W1, Wout, Wcat);
    bias_kernel<<<3, 256, 0, stream>>>(bl, b0, b1, bout, bias);

    const int nb4 = (N_NODES + 3) / 4;

    // ----- layer 1: weights idx 1, edges r2, h_in = x -----
    gather_kernel<<<nb4, 256, 0, stream>>>(xh, rp2, col2, aggb, N_NODES);
    gemm_ln<<<391, 512, 0, stream>>>(aggb, xh, xh, Wcat + 196608,
                                     bias + 256, gamma + 256, beta + 256, h1);

    // ----- layer 2: weights idx 0, edges r1, h_in = h1 -----
    gather_kernel<<<nb4, 256, 0, stream>>>(h1, rp1, col1, aggb, N_NODES);
    gemm_ln<<<391, 512, 0, stream>>>(aggb, h1, xh, Wcat,
                                     bias, gamma, beta, h2);

    // ----- output: d_out = h2 @ Wout^T + bout (fp32) -----
    gemm_bt<<<dim3(391, 1), 256, 0, stream>>>(h2, 256, Wcat + 393216, 256,
                                              bias + 512, (float*)d_out, 128, 256, N_NODES);
}

// Round 6
// 370.576 us; speedup vs baseline: 1.7622x; 1.2044x over previous
//
#include <hip/hip_runtime.h>
#include <stdint.h>

#define N_NODES 50000
#define N_EDGES 500000
#define NPAD    50048   // 391 * 128
#define NB      196     // ceil(50000/256)
#define EPS     1e-5f

typedef _Float16 half8_ __attribute__((ext_vector_type(8)));
typedef _Float16 half4_ __attribute__((ext_vector_type(4)));
typedef float    float4_ __attribute__((ext_vector_type(4)));

typedef uint32_t u32_g __attribute__((address_space(1)));
typedef uint32_t u32_s __attribute__((address_space(3)));

__device__ __forceinline__ void gload16(const void* g, void* lds_wave_base) {
    __builtin_amdgcn_global_load_lds((const u32_g*)g, (u32_s*)lds_wave_base, 16, 0, 0);
}

// ---------------- CSR build ----------------
// Pass A: per-dst counts via atomicAdd; the RETURN VALUE is this edge's rank
// within its dst segment. 4 edges/thread for MLP. grid (489, 2).
__global__ void count_rank_kernel(const int* __restrict__ e1, const int* __restrict__ e2,
                                  int* __restrict__ cnt, int* __restrict__ ranks,
                                  int e, int n) {
    const int set = blockIdx.y;
    const int* dst = set ? e2 : e1;
    int* c = cnt + set * n;
    int* r = ranks + set * e;
    int i0 = (blockIdx.x * 256 + threadIdx.x) * 4;
    if (i0 >= e) return;                       // E % 4 == 0
    int4 d = *(const int4*)(dst + i0);
    int r0 = atomicAdd(&c[d.x], 1);
    int r1 = atomicAdd(&c[d.y], 1);
    int r2 = atomicAdd(&c[d.z], 1);
    int r3 = atomicAdd(&c[d.w], 1);
    *(int4*)(r + i0) = make_int4(r0, r1, r2, r3);
}

__global__ void bsum_kernel(const int* __restrict__ cnt, int* __restrict__ bsums, int n) {
    const int* c = cnt + blockIdx.y * n;
    int i = blockIdx.x * 256 + threadIdx.x;
    int v = (i < n) ? c[i] : 0;
    for (int off = 32; off > 0; off >>= 1) v += __shfl_xor(v, off, 64);
    __shared__ int ws[4];
    if ((threadIdx.x & 63) == 0) ws[threadIdx.x >> 6] = v;
    __syncthreads();
    if (threadIdx.x == 0)
        bsums[blockIdx.y * 256 + blockIdx.x] = ws[0] + ws[1] + ws[2] + ws[3];
}

__global__ void bscan_kernel(int* __restrict__ bsums, int* __restrict__ rp1,
                             int* __restrict__ rp2, int nb, int n) {
    __shared__ int sm[512];
    int t = threadIdx.x;
    int idx = t & 255;
    int v = (idx < nb) ? bsums[t] : 0;
    sm[t] = v;
    __syncthreads();
    for (int off = 1; off < 256; off <<= 1) {
        int x = sm[t];
        if (idx >= off) x += sm[t - off];
        __syncthreads();
        sm[t] = x;
        __syncthreads();
    }
    if (idx < nb) bsums[t] = (idx > 0) ? sm[t - 1] : 0;
    if (t == 255)  rp1[n] = sm[255];
    if (t == 511)  rp2[n] = sm[511];
}

__global__ void bscatter_kernel(const int* __restrict__ cnt, const int* __restrict__ bsums,
                                int* __restrict__ rp, int n) {
    const int* c = cnt + blockIdx.y * n;
    int* rpS = rp + blockIdx.y * (n + 1);
    __shared__ int sm[256];
    int t = threadIdx.x;
    int i = blockIdx.x * 256 + t;
    int v = (i < n) ? c[i] : 0;
    sm[t] = v;
    __syncthreads();
    for (int off = 1; off < 256; off <<= 1) {
        int x = sm[t];
        if (t >= off) x += sm[t - off];
        __syncthreads();
        sm[t] = x;
        __syncthreads();
    }
    int excl = sm[t] - v + bsums[blockIdx.y * 256 + blockIdx.x];
    if (i < n) rpS[i] = excl;
}

// Pass B: atomic-free placement. col[rowptr[dst] + rank] = src. grid (489, 2).
__global__ void place_kernel(const int* __restrict__ e1, const int* __restrict__ e2,
                             const int* __restrict__ ranks, const int* __restrict__ rp,
                             int* __restrict__ col, int e, int n) {
    const int set = blockIdx.y;
    const int* ed = set ? e2 : e1;
    const int* r  = ranks + set * e;
    const int* rpS = rp + set * (n + 1);
    int* cl = col + set * e;
    int i0 = (blockIdx.x * 256 + threadIdx.x) * 4;
    if (i0 >= e) return;
    int4 d  = *(const int4*)(ed + i0);
    int4 s  = *(const int4*)(ed + e + i0);
    int4 rk = *(const int4*)(r + i0);
    int p0 = rpS[d.x] + rk.x;
    int p1 = rpS[d.y] + rk.y;
    int p2 = rpS[d.z] + rk.z;
    int p3 = rpS[d.w] + rk.w;
    cl[p0] = s.x; cl[p1] = s.y; cl[p2] = s.z; cl[p3] = s.w;
}

// ---------------- staging ----------------
__global__ void copyx_kernel(const float* __restrict__ x, _Float16* __restrict__ xh, int n) {
    int i = blockIdx.x * 256 + threadIdx.x;
    if (i >= n * 64) return;
    float4_ v = ((const float4_*)x)[i];
    half4_ h;
    h[0] = (_Float16)v[0]; h[1] = (_Float16)v[1];
    h[2] = (_Float16)v[2]; h[3] = (_Float16)v[3];
    ((half4_*)xh)[i] = h;
}

__global__ void pad_kernel(_Float16* __restrict__ a, _Float16* __restrict__ b,
                           _Float16* __restrict__ c, _Float16* __restrict__ d) {
    int i = blockIdx.x * 256 + threadIdx.x;
    int buf = i / 3072, j = i % 3072;
    _Float16* p = (buf == 0) ? a : (buf == 1) ? b : (buf == 2) ? c : d;
    half4_ z = {(_Float16)0.f, (_Float16)0.f, (_Float16)0.f, (_Float16)0.f};
    *(half4_*)(p + (size_t)N_NODES * 256 + (size_t)j * 4) = z;
}

__global__ void wcat_kernel(const float* __restrict__ Wl, const float* __restrict__ W0,
                            const float* __restrict__ W1, const float* __restrict__ Wout,
                            _Float16* __restrict__ Wcat) {
    int i = blockIdx.x * 256 + threadIdx.x;
    if (i < 2 * 256 * 768) {
        int l = i / (256 * 768);
        int r = i % (256 * 768);
        int j = r / 768, k = r % 768;
        const float* s = (k < 256) ? Wl : (k < 512 ? W0 : W1);
        Wcat[i] = (_Float16)s[l * 65536 + j * 256 + (k & 255)];
    } else if (i < 2 * 256 * 768 + 128 * 256) {
        int r = i - 2 * 256 * 768;
        Wcat[i] = (_Float16)Wout[r];
    }
}

__global__ void bias_kernel(const float* __restrict__ bl, const float* __restrict__ b0,
                            const float* __restrict__ b1, const float* __restrict__ bout,
                            float* __restrict__ bias) {
    int i = blockIdx.x * 256 + threadIdx.x;
    if (i < 512)       bias[i] = bl[i] + b0[i] + b1[i];
    else if (i < 640)  bias[i] = bout[i - 512];
}

// ---------------- CSR pull gather, 2x unrolled for MLP ----------------
__global__ void gather_kernel(const _Float16* __restrict__ hin,
                              const int* __restrict__ rowptr, const int* __restrict__ col,
                              _Float16* __restrict__ dst, int n) {
    int node = blockIdx.x * 4 + (threadIdx.x >> 6);
    int l = threadIdx.x & 63;
    if (node >= n) return;
    int s = rowptr[node], e = rowptr[node + 1];
    float a0 = 0.f, a1 = 0.f, a2 = 0.f, a3 = 0.f;
    float b0 = 0.f, b1 = 0.f, b2 = 0.f, b3 = 0.f;
    int i = s;
    for (; i + 1 < e; i += 2) {
        int c0 = col[i], c1 = col[i + 1];
        half4_ v0 = *(const half4_*)(hin + (size_t)c0 * 256 + l * 4);
        half4_ v1 = *(const half4_*)(hin + (size_t)c1 * 256 + l * 4);
        a0 += (float)v0[0]; a1 += (float)v0[1]; a2 += (float)v0[2]; a3 += (float)v0[3];
        b0 += (float)v1[0]; b1 += (float)v1[1]; b2 += (float)v1[2]; b3 += (float)v1[3];
    }
    if (i < e) {
        int c0 = col[i];
        half4_ v0 = *(const half4_*)(hin + (size_t)c0 * 256 + l * 4);
        a0 += (float)v0[0]; a1 += (float)v0[1]; a2 += (float)v0[2]; a3 += (float)v0[3];
    }
    half4_ o = { (_Float16)(a0 + b0), (_Float16)(a1 + b1),
                 (_Float16)(a2 + b2), (_Float16)(a3 + b3) };
    *(half4_*)(dst + (size_t)node * 256 + l * 4) = o;
}

// ---------------- fused layer GEMM: H = LN(relu([agg|h|x] @ W^T + bias)) ----------------
__global__ __launch_bounds__(512) void gemm_ln(const _Float16* __restrict__ agg,
                                               const _Float16* __restrict__ hsrc,
                                               const _Float16* __restrict__ xh,
                                               const _Float16* __restrict__ Bw,  // [256][768]
                                               const float* __restrict__ bias,
                                               const float* __restrict__ gamma,
                                               const float* __restrict__ beta,
                                               _Float16* __restrict__ H) {
    __shared__ __align__(16) char smem[49152];   // As 16K | Bs 32K
    char* AsB = smem;
    char* BsB = smem + 16384;
    const int rowBase = blockIdx.x * 128;
    const int tid  = threadIdx.x;
    const int lane = tid & 63;
    const int w    = tid >> 6;
    const int wm = w & 1, wn = w >> 1;
    const int quad = lane >> 4, mr = lane & 15;
    const int x7 = mr & 7;

    float4_ acc[4][4];
#pragma unroll
    for (int i = 0; i < 4; i++)
#pragma unroll
        for (int j = 0; j < 4; j++) { float4_ z4 = {0.f, 0.f, 0.f, 0.f}; acc[i][j] = z4; }

    int cA0 = w * 64 + lane, cA1 = cA0 + 512;
    int rA0 = cA0 >> 3, rA1 = cA1 >> 3;
    size_t offA0 = (size_t)(rowBase + rA0) * 256 + (((cA0 & 7) ^ (rA0 & 7)) * 8);
    size_t offA1 = (size_t)(rowBase + rA1) * 256 + (((cA1 & 7) ^ (rA1 & 7)) * 8);
    size_t offB[4];
#pragma unroll
    for (int j = 0; j < 4; j++) {
        int c = j * 512 + w * 64 + lane;
        int r = c >> 3;
        offB[j] = (size_t)r * 768 + (((c & 7) ^ (r & 7)) * 8);
    }
    void* lA0 = AsB + w * 1024;
    void* lA1 = AsB + 8192 + w * 1024;

    for (int k0 = 0; k0 < 768; k0 += 64) {
        const _Float16* src = (k0 < 256) ? agg : (k0 < 512) ? hsrc : xh;
        const int kloc = k0 & 255;
        gload16(src + offA0 + kloc, lA0);
        gload16(src + offA1 + kloc, lA1);
        gload16(Bw + offB[0] + k0, BsB + w * 1024);
        gload16(Bw + offB[1] + k0, BsB + 8192 + w * 1024);
        gload16(Bw + offB[2] + k0, BsB + 16384 + w * 1024);
        gload16(Bw + offB[3] + k0, BsB + 24576 + w * 1024);
        __syncthreads();
#pragma unroll
        for (int s = 0; s < 2; s++) {
            half8_ a[4], b[4];
#pragma unroll
            for (int im = 0; im < 4; im++) {
                int row = wm * 64 + im * 16 + mr;
                a[im] = *(const half8_*)(AsB + row * 128 + (((s * 4 + quad) ^ x7) * 16));
            }
#pragma unroll
            for (int in = 0; in < 4; in++) {
                int row = wn * 64 + in * 16 + mr;
                b[in] = *(const half8_*)(BsB + row * 128 + (((s * 4 + quad) ^ x7) * 16));
            }
#pragma unroll
            for (int im = 0; im < 4; im++)
#pragma unroll
                for (int in = 0; in < 4; in++)
                    acc[im][in] = __builtin_amdgcn_mfma_f32_16x16x32_f16(a[im], b[in], acc[im][in], 0, 0, 0);
        }
        __syncthreads();
    }

    float bv[4], gv[4], bev[4];
#pragma unroll
    for (int in = 0; in < 4; in++) {
        int colg = wn * 64 + in * 16 + mr;
        bv[in]  = bias[colg];
        gv[in]  = gamma[colg];
        bev[in] = beta[colg];
    }
    float* lnbuf   = (float*)AsB;
    float* lnstats = (float*)(AsB + 4096);

#pragma unroll
    for (int im = 0; im < 4; im++)
#pragma unroll
        for (int r = 0; r < 4; r++) {
            float s = 0.f, sq = 0.f;
#pragma unroll
            for (int in = 0; in < 4; in++) {
                float v = acc[im][in][r] + bv[in];
                v = v > 0.f ? v : 0.f;
                s += v; sq += v * v;
            }
            s  += __shfl_xor(s, 1, 64);  sq += __shfl_xor(sq, 1, 64);
            s  += __shfl_xor(s, 2, 64);  sq += __shfl_xor(sq, 2, 64);
            s  += __shfl_xor(s, 4, 64);  sq += __shfl_xor(sq, 4, 64);
            s  += __shfl_xor(s, 8, 64);  sq += __shfl_xor(sq, 8, 64);
            if (mr == 0) {
                int rl = wm * 64 + im * 16 + quad * 4 + r;
                lnbuf[(wn * 128 + rl) * 2]     = s;
                lnbuf[(wn * 128 + rl) * 2 + 1] = sq;
            }
        }
    __syncthreads();
    if (tid < 128) {
        float s  = lnbuf[tid * 2]             + lnbuf[(128 + tid) * 2]
                 + lnbuf[(256 + tid) * 2]     + lnbuf[(384 + tid) * 2];
        float sq = lnbuf[tid * 2 + 1]         + lnbuf[(128 + tid) * 2 + 1]
                 + lnbuf[(256 + tid) * 2 + 1] + lnbuf[(384 + tid) * 2 + 1];
        float mu  = s * (1.0f / 256.0f);
        float var = sq * (1.0f / 256.0f) - mu * mu;
        lnstats[tid * 2]     = mu;
        lnstats[tid * 2 + 1] = rsqrtf(var + EPS);
    }
    __syncthreads();

    _Float16* BsH = (_Float16*)BsB;
#pragma unroll
    for (int p = 0; p < 2; p++) {
        if (wm == p) {
#pragma unroll
            for (int im = 0; im < 4; im++)
#pragma unroll
                for (int r = 0; r < 4; r++) {
                    int rl = im * 16 + quad * 4 + r;
                    float mu = lnstats[(p * 64 + rl) * 2];
                    float rs = lnstats[(p * 64 + rl) * 2 + 1];
#pragma unroll
                    for (int in = 0; in < 4; in++) {
                        float v = acc[im][in][r] + bv[in];
                        v = v > 0.f ? v : 0.f;
                        BsH[rl * 256 + wn * 64 + in * 16 + mr] =
                            (_Float16)((v - mu) * rs * gv[in] + bev[in]);
                    }
                }
        }
        __syncthreads();
#pragma unroll
        for (int i = 0; i < 4; i++) {
            int c = i * 512 + tid;
            int row = c >> 5, ch = c & 31;
            half8_ v = *(const half8_*)(BsB + c * 16);
            *(half8_*)(H + (size_t)(rowBase + p * 64 + row) * 256 + ch * 8) = v;
        }
        __syncthreads();
    }
}

// ---------------- final GEMM: d_out = h2 @ Wout^T + bout (fp32) ----------------
__global__ __launch_bounds__(256) void gemm_bt(const _Float16* __restrict__ A, int lda,
                                               const _Float16* __restrict__ B, int ldb,
                                               const float* __restrict__ bias,
                                               float* __restrict__ C, int ldc,
                                               int K, int Mstore) {
    __shared__ _Float16 As[128 * 32];
    __shared__ _Float16 Bs[128 * 32];
    const int rowBase = blockIdx.x * 128;
    const int colBase = blockIdx.y * 128;
    const int tid  = threadIdx.x;
    const int lane = tid & 63;
    const int w    = tid >> 6;
    const int wm = w & 1, wn = w >> 1;
    const int quad = lane >> 4, mr = lane & 15;

    float4_ acc[4][4];
#pragma unroll
    for (int i = 0; i < 4; i++)
#pragma unroll
        for (int j = 0; j < 4; j++) { float4_ z4 = {0.f, 0.f, 0.f, 0.f}; acc[i][j] = z4; }

    const int c0  = w * 64 + lane;
    const int rA0 = c0 >> 2;
    const int ko  = (c0 & 3) * 8;
    char* AsB = (char*)As;
    char* BsB = (char*)Bs;
    void* lA0 = AsB + w * 1024;
    void* lA1 = AsB + 4096 + w * 1024;
    void* lB0 = BsB + w * 1024;
    void* lB1 = BsB + 4096 + w * 1024;
    const _Float16* gA0 = A + (size_t)(rowBase + rA0) * lda + ko;
    const _Float16* gA1 = gA0 + (size_t)64 * lda;
    const _Float16* gB0 = B + (size_t)(colBase + rA0) * ldb + ko;
    const _Float16* gB1 = gB0 + (size_t)64 * ldb;

    for (int k0 = 0; k0 < K; k0 += 32) {
        gload16(gA0 + k0, lA0);
        gload16(gA1 + k0, lA1);
        gload16(gB0 + k0, lB0);
        gload16(gB1 + k0, lB1);
        __syncthreads();
        half8_ a[4], b[4];
#pragma unroll
        for (int im = 0; im < 4; im++)
            a[im] = *(const half8_*)(AsB + ((wm * 64 + im * 16 + mr) * 64 + quad * 16));
#pragma unroll
        for (int in = 0; in < 4; in++)
            b[in] = *(const half8_*)(BsB + ((wn * 64 + in * 16 + mr) * 64 + quad * 16));
#pragma unroll
        for (int im = 0; im < 4; im++)
#pragma unroll
            for (int in = 0; in < 4; in++)
                acc[im][in] = __builtin_amdgcn_mfma_f32_16x16x32_f16(a[im], b[in], acc[im][in], 0, 0, 0);
        __syncthreads();
    }

#pragma unroll
    for (int in = 0; in < 4; in++) {
        const int colg = colBase + wn * 64 + in * 16 + mr;
        const float bv = bias[colg];
#pragma unroll
        for (int im = 0; im < 4; im++) {
            float4_ c = acc[im][in];
#pragma unroll
            for (int r = 0; r < 4; r++) {
                int row = rowBase + wm * 64 + im * 16 + quad * 4 + r;
                if (row < Mstore) C[(size_t)row * ldc + colg] = c[r] + bv;
            }
        }
    }
}

extern "C" void kernel_launch(void* const* d_in, const int* in_sizes, int n_in,
                              void* d_out, int out_size, void* d_ws, size_t ws_size,
                              hipStream_t stream) {
    const float* x    = (const float*)d_in[0];
    const int*   e1   = (const int*)d_in[1];
    const int*   e2   = (const int*)d_in[2];
    const float* Wl   = (const float*)d_in[3];
    const float* bl   = (const float*)d_in[4];
    const float* W0   = (const float*)d_in[5];
    const float* b0   = (const float*)d_in[6];
    const float* W1   = (const float*)d_in[7];
    const float* b1   = (const float*)d_in[8];
    const float* gamma= (const float*)d_in[9];
    const float* beta = (const float*)d_in[10];
    const float* Wout = (const float*)d_in[11];
    const float* bout = (const float*)d_in[12];

    char* ws = (char*)d_ws;
    size_t off = 0;
    auto alloc = [&](size_t bytes) -> char* {
        char* p = ws + off;
        off = (off + bytes + 255) & ~(size_t)255;
        return p;
    };
    _Float16* xh   = (_Float16*)alloc((size_t)NPAD * 256 * 2);
    _Float16* aggb = (_Float16*)alloc((size_t)NPAD * 256 * 2);
    _Float16* h1   = (_Float16*)alloc((size_t)NPAD * 256 * 2);
    _Float16* h2   = (_Float16*)alloc((size_t)NPAD * 256 * 2);
    _Float16* Wcat = (_Float16*)alloc((size_t)(2 * 256 * 768 + 128 * 256) * 2);
    float*    bias = (float*)alloc(640 * 4);
    int* cnt   = (int*)alloc((size_t)2 * N_NODES * 4);
    int* rp    = (int*)alloc((size_t)2 * (N_NODES + 1) * 4);
    int* ranks = (int*)alloc((size_t)2 * N_EDGES * 4);
    int* col   = (int*)alloc((size_t)2 * N_EDGES * 4);
    int* bsums = (int*)alloc(512 * 4);

    int* rp1 = rp, *rp2 = rp + (N_NODES + 1);
    int* col1 = col, *col2 = col + N_EDGES;

    hipMemsetAsync(cnt, 0, (size_t)2 * N_NODES * 4, stream);

    const int eb4 = (N_EDGES / 4 + 255) / 256;   // 489
    count_rank_kernel<<<dim3(eb4, 2), 256, 0, stream>>>(e1, e2, cnt, ranks, N_EDGES, N_NODES);
    bsum_kernel<<<dim3(NB, 2), 256, 0, stream>>>(cnt, bsums, N_NODES);
    bscan_kernel<<<1, 512, 0, stream>>>(bsums, rp1, rp2, NB, N_NODES);
    bscatter_kernel<<<dim3(NB, 2), 256, 0, stream>>>(cnt, bsums, rp, N_NODES);
    place_kernel<<<dim3(eb4, 2), 256, 0, stream>>>(e1, e2, ranks, rp, col, N_EDGES, N_NODES);

    copyx_kernel<<<12500, 256, 0, stream>>>(x, xh, N_NODES);
    pad_kernel<<<48, 256, 0, stream>>>(xh, aggb, h1, h2);
    wcat_kernel<<<(2 * 256 * 768 + 128 * 256 + 255) / 256, 256, 0, stream>>>(Wl, W0, W1, Wout, Wcat);
    bias_kernel<<<3, 256, 0, stream>>>(bl, b0, b1, bout, bias);

    const int nb4 = (N_NODES + 3) / 4;

    // ----- layer 1: weights idx 1, edges r2, h_in = x -----
    gather_kernel<<<nb4, 256, 0, stream>>>(xh, rp2, col2, aggb, N_NODES);
    gemm_ln<<<391, 512, 0, stream>>>(aggb, xh, xh, Wcat + 196608,
                                     bias + 256, gamma + 256, beta + 256, h1);

    // ----- layer 2: weights idx 0, edges r1, h_in = h1 -----
    gather_kernel<<<nb4, 256, 0, stream>>>(h1, rp1, col1, aggb, N_NODES);
    gemm_ln<<<391, 512, 0, stream>>>(aggb, h1, xh, Wcat,
                                     bias, gamma, beta, h2);

    // ----- output: d_out = h2 @ Wout^T + bout (fp32) -----
    gemm_bt<<<dim3(391, 1), 256, 0, stream>>>(h2, 256, Wcat + 393216, 256,
                                              bias + 512, (float*)d_out, 128, 256, N_NODES);
}

// Round 7
// 347.721 us; speedup vs baseline: 1.8780x; 1.0657x over previous
//
#include <hip/hip_runtime.h>
#include <stdint.h>

#define N_NODES 50000
#define N_EDGES 500000
#define NPAD    50048   // 391 * 128
#define NB      196     // ceil(50000/256)
#define EPS     1e-5f

typedef _Float16 half8_ __attribute__((ext_vector_type(8)));
typedef _Float16 half4_ __attribute__((ext_vector_type(4)));
typedef float    float4_ __attribute__((ext_vector_type(4)));

typedef uint32_t u32_g __attribute__((address_space(1)));
typedef uint32_t u32_s __attribute__((address_space(3)));

__device__ __forceinline__ void gload16(const void* g, void* lds_wave_base) {
    __builtin_amdgcn_global_load_lds((const u32_g*)g, (u32_s*)lds_wave_base, 16, 0, 0);
}

// ---------------- CSR build ----------------
// Pass A: per-dst counts via atomicAdd; return value = edge's rank in its segment.
// 8 edges/thread for MLP. grid (245, 2).
__global__ void count_rank_kernel(const int* __restrict__ e1, const int* __restrict__ e2,
                                  int* __restrict__ cnt, int* __restrict__ ranks,
                                  int e, int n) {
    const int set = blockIdx.y;
    const int* dst = set ? e2 : e1;
    int* c = cnt + set * n;
    int* r = ranks + set * e;
    int i0 = (blockIdx.x * 256 + threadIdx.x) * 8;
    if (i0 >= e) return;                       // E % 8 == 0
    int4 d0 = *(const int4*)(dst + i0);
    int4 d1 = *(const int4*)(dst + i0 + 4);
    int r0 = atomicAdd(&c[d0.x], 1);
    int r1 = atomicAdd(&c[d0.y], 1);
    int r2 = atomicAdd(&c[d0.z], 1);
    int r3 = atomicAdd(&c[d0.w], 1);
    int r4 = atomicAdd(&c[d1.x], 1);
    int r5 = atomicAdd(&c[d1.y], 1);
    int r6 = atomicAdd(&c[d1.z], 1);
    int r7 = atomicAdd(&c[d1.w], 1);
    *(int4*)(r + i0)     = make_int4(r0, r1, r2, r3);
    *(int4*)(r + i0 + 4) = make_int4(r4, r5, r6, r7);
}

__global__ void bsum_kernel(const int* __restrict__ cnt, int* __restrict__ bsums, int n) {
    const int* c = cnt + blockIdx.y * n;
    int i = blockIdx.x * 256 + threadIdx.x;
    int v = (i < n) ? c[i] : 0;
    for (int off = 32; off > 0; off >>= 1) v += __shfl_xor(v, off, 64);
    __shared__ int ws[4];
    if ((threadIdx.x & 63) == 0) ws[threadIdx.x >> 6] = v;
    __syncthreads();
    if (threadIdx.x == 0)
        bsums[blockIdx.y * 256 + blockIdx.x] = ws[0] + ws[1] + ws[2] + ws[3];
}

__global__ void bscan_kernel(int* __restrict__ bsums, int* __restrict__ rp1,
                             int* __restrict__ rp2, int nb, int n) {
    __shared__ int sm[512];
    int t = threadIdx.x;
    int idx = t & 255;
    int v = (idx < nb) ? bsums[t] : 0;
    sm[t] = v;
    __syncthreads();
    for (int off = 1; off < 256; off <<= 1) {
        int x = sm[t];
        if (idx >= off) x += sm[t - off];
        __syncthreads();
        sm[t] = x;
        __syncthreads();
    }
    if (idx < nb) bsums[t] = (idx > 0) ? sm[t - 1] : 0;
    if (t == 255)  rp1[n] = sm[255];
    if (t == 511)  rp2[n] = sm[511];
}

__global__ void bscatter_kernel(const int* __restrict__ cnt, const int* __restrict__ bsums,
                                int* __restrict__ rp, int n) {
    const int* c = cnt + blockIdx.y * n;
    int* rpS = rp + blockIdx.y * (n + 1);
    __shared__ int sm[256];
    int t = threadIdx.x;
    int i = blockIdx.x * 256 + t;
    int v = (i < n) ? c[i] : 0;
    sm[t] = v;
    __syncthreads();
    for (int off = 1; off < 256; off <<= 1) {
        int x = sm[t];
        if (t >= off) x += sm[t - off];
        __syncthreads();
        sm[t] = x;
        __syncthreads();
    }
    int excl = sm[t] - v + bsums[blockIdx.y * 256 + blockIdx.x];
    if (i < n) rpS[i] = excl;
}

// Pass B: atomic-free placement. col[rowptr[dst] + rank] = src. grid (245, 2).
__global__ void place_kernel(const int* __restrict__ e1, const int* __restrict__ e2,
                             const int* __restrict__ ranks, const int* __restrict__ rp,
                             int* __restrict__ col, int e, int n) {
    const int set = blockIdx.y;
    const int* ed = set ? e2 : e1;
    const int* r  = ranks + set * e;
    const int* rpS = rp + set * (n + 1);
    int* cl = col + set * e;
    int i0 = (blockIdx.x * 256 + threadIdx.x) * 8;
    if (i0 >= e) return;
    int4 d0 = *(const int4*)(ed + i0);
    int4 d1 = *(const int4*)(ed + i0 + 4);
    int4 s0 = *(const int4*)(ed + e + i0);
    int4 s1 = *(const int4*)(ed + e + i0 + 4);
    int4 k0 = *(const int4*)(r + i0);
    int4 k1 = *(const int4*)(r + i0 + 4);
    int p0 = rpS[d0.x] + k0.x;
    int p1 = rpS[d0.y] + k0.y;
    int p2 = rpS[d0.z] + k0.z;
    int p3 = rpS[d0.w] + k0.w;
    int p4 = rpS[d1.x] + k1.x;
    int p5 = rpS[d1.y] + k1.y;
    int p6 = rpS[d1.z] + k1.z;
    int p7 = rpS[d1.w] + k1.w;
    cl[p0] = s0.x; cl[p1] = s0.y; cl[p2] = s0.z; cl[p3] = s0.w;
    cl[p4] = s1.x; cl[p5] = s1.y; cl[p6] = s1.z; cl[p7] = s1.w;
}

// ---------------- staging ----------------
__global__ void copyx_kernel(const float* __restrict__ x, _Float16* __restrict__ xh, int n) {
    int i = blockIdx.x * 256 + threadIdx.x;
    if (i >= n * 64) return;
    float4_ v = ((const float4_*)x)[i];
    half4_ h;
    h[0] = (_Float16)v[0]; h[1] = (_Float16)v[1];
    h[2] = (_Float16)v[2]; h[3] = (_Float16)v[3];
    ((half4_*)xh)[i] = h;
}

__global__ void pad_kernel(_Float16* __restrict__ a, _Float16* __restrict__ b,
                           _Float16* __restrict__ c, _Float16* __restrict__ d) {
    int i = blockIdx.x * 256 + threadIdx.x;
    int buf = i / 3072, j = i % 3072;
    _Float16* p = (buf == 0) ? a : (buf == 1) ? b : (buf == 2) ? c : d;
    half4_ z = {(_Float16)0.f, (_Float16)0.f, (_Float16)0.f, (_Float16)0.f};
    *(half4_*)(p + (size_t)N_NODES * 256 + (size_t)j * 4) = z;
}

__global__ void wcat_kernel(const float* __restrict__ Wl, const float* __restrict__ W0,
                            const float* __restrict__ W1, const float* __restrict__ Wout,
                            _Float16* __restrict__ Wcat) {
    int i = blockIdx.x * 256 + threadIdx.x;
    if (i < 2 * 256 * 768) {
        int l = i / (256 * 768);
        int r = i % (256 * 768);
        int j = r / 768, k = r % 768;
        const float* s = (k < 256) ? Wl : (k < 512 ? W0 : W1);
        Wcat[i] = (_Float16)s[l * 65536 + j * 256 + (k & 255)];
    } else if (i < 2 * 256 * 768 + 128 * 256) {
        int r = i - 2 * 256 * 768;
        Wcat[i] = (_Float16)Wout[r];
    }
}

__global__ void bias_kernel(const float* __restrict__ bl, const float* __restrict__ b0,
                            const float* __restrict__ b1, const float* __restrict__ bout,
                            float* __restrict__ bias) {
    int i = blockIdx.x * 256 + threadIdx.x;
    if (i < 512)       bias[i] = bl[i] + b0[i] + b1[i];
    else if (i < 640)  bias[i] = bout[i - 512];
}

// ---------------- CSR pull gather: split-wave, 16B/lane, 4 rows in flight ----------------
// 32 lanes cover one 512B row; the two wave halves process different edges.
__global__ void gather_kernel(const _Float16* __restrict__ hin,
                              const int* __restrict__ rowptr, const int* __restrict__ col,
                              _Float16* __restrict__ dst, int n) {
    int node = blockIdx.x * 4 + (threadIdx.x >> 6);
    int lane = threadIdx.x & 63;
    int half = lane >> 5, l5 = lane & 31;
    if (node >= n) return;
    int s = rowptr[node], e = rowptr[node + 1];
    float a[8] = {0.f, 0.f, 0.f, 0.f, 0.f, 0.f, 0.f, 0.f};
    float b[8] = {0.f, 0.f, 0.f, 0.f, 0.f, 0.f, 0.f, 0.f};
    int i = s + half;
    // edges i, i+2 per iteration (each half strides 2, unroll 2)
    for (; i + 2 < e; i += 4) {
        int c0 = col[i], c1 = col[i + 2];
        half8_ v0 = *(const half8_*)(hin + (size_t)c0 * 256 + l5 * 8);
        half8_ v1 = *(const half8_*)(hin + (size_t)c1 * 256 + l5 * 8);
#pragma unroll
        for (int j = 0; j < 8; j++) { a[j] += (float)v0[j]; b[j] += (float)v1[j]; }
    }
    for (; i < e; i += 2) {
        int c0 = col[i];
        half8_ v0 = *(const half8_*)(hin + (size_t)c0 * 256 + l5 * 8);
#pragma unroll
        for (int j = 0; j < 8; j++) a[j] += (float)v0[j];
    }
    half8_ o;
#pragma unroll
    for (int j = 0; j < 8; j++) {
        float t = a[j] + b[j];
        t += __shfl_xor(t, 32, 64);          // combine the two halves
        o[j] = (_Float16)t;
    }
    if (half == 0)
        *(half8_*)(dst + (size_t)node * 256 + l5 * 8) = o;
}

// ---------------- fused layer GEMM: H = LN(relu([agg|h|x] @ W^T + bias)) ----------------
__global__ __launch_bounds__(512) void gemm_ln(const _Float16* __restrict__ agg,
                                               const _Float16* __restrict__ hsrc,
                                               const _Float16* __restrict__ xh,
                                               const _Float16* __restrict__ Bw,  // [256][768]
                                               const float* __restrict__ bias,
                                               const float* __restrict__ gamma,
                                               const float* __restrict__ beta,
                                               _Float16* __restrict__ H) {
    __shared__ __align__(16) char smem[49152];   // As 16K | Bs 32K
    char* AsB = smem;
    char* BsB = smem + 16384;
    const int rowBase = blockIdx.x * 128;
    const int tid  = threadIdx.x;
    const int lane = tid & 63;
    const int w    = tid >> 6;
    const int wm = w & 1, wn = w >> 1;
    const int quad = lane >> 4, mr = lane & 15;
    const int x7 = mr & 7;

    float4_ acc[4][4];
#pragma unroll
    for (int i = 0; i < 4; i++)
#pragma unroll
        for (int j = 0; j < 4; j++) { float4_ z4 = {0.f, 0.f, 0.f, 0.f}; acc[i][j] = z4; }

    int cA0 = w * 64 + lane, cA1 = cA0 + 512;
    int rA0 = cA0 >> 3, rA1 = cA1 >> 3;
    size_t offA0 = (size_t)(rowBase + rA0) * 256 + (((cA0 & 7) ^ (rA0 & 7)) * 8);
    size_t offA1 = (size_t)(rowBase + rA1) * 256 + (((cA1 & 7) ^ (rA1 & 7)) * 8);
    size_t offB[4];
#pragma unroll
    for (int j = 0; j < 4; j++) {
        int c = j * 512 + w * 64 + lane;
        int r = c >> 3;
        offB[j] = (size_t)r * 768 + (((c & 7) ^ (r & 7)) * 8);
    }
    void* lA0 = AsB + w * 1024;
    void* lA1 = AsB + 8192 + w * 1024;

    for (int k0 = 0; k0 < 768; k0 += 64) {
        const _Float16* src = (k0 < 256) ? agg : (k0 < 512) ? hsrc : xh;
        const int kloc = k0 & 255;
        gload16(src + offA0 + kloc, lA0);
        gload16(src + offA1 + kloc, lA1);
        gload16(Bw + offB[0] + k0, BsB + w * 1024);
        gload16(Bw + offB[1] + k0, BsB + 8192 + w * 1024);
        gload16(Bw + offB[2] + k0, BsB + 16384 + w * 1024);
        gload16(Bw + offB[3] + k0, BsB + 24576 + w * 1024);
        __syncthreads();
#pragma unroll
        for (int s = 0; s < 2; s++) {
            half8_ a[4], b[4];
#pragma unroll
            for (int im = 0; im < 4; im++) {
                int row = wm * 64 + im * 16 + mr;
                a[im] = *(const half8_*)(AsB + row * 128 + (((s * 4 + quad) ^ x7) * 16));
            }
#pragma unroll
            for (int in = 0; in < 4; in++) {
                int row = wn * 64 + in * 16 + mr;
                b[in] = *(const half8_*)(BsB + row * 128 + (((s * 4 + quad) ^ x7) * 16));
            }
#pragma unroll
            for (int im = 0; im < 4; im++)
#pragma unroll
                for (int in = 0; in < 4; in++)
                    acc[im][in] = __builtin_amdgcn_mfma_f32_16x16x32_f16(a[im], b[in], acc[im][in], 0, 0, 0);
        }
        __syncthreads();
    }

    float bv[4], gv[4], bev[4];
#pragma unroll
    for (int in = 0; in < 4; in++) {
        int colg = wn * 64 + in * 16 + mr;
        bv[in]  = bias[colg];
        gv[in]  = gamma[colg];
        bev[in] = beta[colg];
    }
    float* lnbuf   = (float*)AsB;
    float* lnstats = (float*)(AsB + 4096);

#pragma unroll
    for (int im = 0; im < 4; im++)
#pragma unroll
        for (int r = 0; r < 4; r++) {
            float s = 0.f, sq = 0.f;
#pragma unroll
            for (int in = 0; in < 4; in++) {
                float v = acc[im][in][r] + bv[in];
                v = v > 0.f ? v : 0.f;
                s += v; sq += v * v;
            }
            s  += __shfl_xor(s, 1, 64);  sq += __shfl_xor(sq, 1, 64);
            s  += __shfl_xor(s, 2, 64);  sq += __shfl_xor(sq, 2, 64);
            s  += __shfl_xor(s, 4, 64);  sq += __shfl_xor(sq, 4, 64);
            s  += __shfl_xor(s, 8, 64);  sq += __shfl_xor(sq, 8, 64);
            if (mr == 0) {
                int rl = wm * 64 + im * 16 + quad * 4 + r;
                lnbuf[(wn * 128 + rl) * 2]     = s;
                lnbuf[(wn * 128 + rl) * 2 + 1] = sq;
            }
        }
    __syncthreads();
    if (tid < 128) {
        float s  = lnbuf[tid * 2]             + lnbuf[(128 + tid) * 2]
                 + lnbuf[(256 + tid) * 2]     + lnbuf[(384 + tid) * 2];
        float sq = lnbuf[tid * 2 + 1]         + lnbuf[(128 + tid) * 2 + 1]
                 + lnbuf[(256 + tid) * 2 + 1] + lnbuf[(384 + tid) * 2 + 1];
        float mu  = s * (1.0f / 256.0f);
        float var = sq * (1.0f / 256.0f) - mu * mu;
        lnstats[tid * 2]     = mu;
        lnstats[tid * 2 + 1] = rsqrtf(var + EPS);
    }
    __syncthreads();

    _Float16* BsH = (_Float16*)BsB;
#pragma unroll
    for (int p = 0; p < 2; p++) {
        if (wm == p) {
#pragma unroll
            for (int im = 0; im < 4; im++)
#pragma unroll
                for (int r = 0; r < 4; r++) {
                    int rl = im * 16 + quad * 4 + r;
                    float mu = lnstats[(p * 64 + rl) * 2];
                    float rs = lnstats[(p * 64 + rl) * 2 + 1];
#pragma unroll
                    for (int in = 0; in < 4; in++) {
                        float v = acc[im][in][r] + bv[in];
                        v = v > 0.f ? v : 0.f;
                        BsH[rl * 256 + wn * 64 + in * 16 + mr] =
                            (_Float16)((v - mu) * rs * gv[in] + bev[in]);
                    }
                }
        }
        __syncthreads();
#pragma unroll
        for (int i = 0; i < 4; i++) {
            int c = i * 512 + tid;
            int row = c >> 5, ch = c & 31;
            half8_ v = *(const half8_*)(BsB + c * 16);
            *(half8_*)(H + (size_t)(rowBase + p * 64 + row) * 256 + ch * 8) = v;
        }
        __syncthreads();
    }
}

// ---------------- final GEMM: d_out = h2 @ Wout^T + bout (fp32) ----------------
__global__ __launch_bounds__(256) void gemm_bt(const _Float16* __restrict__ A, int lda,
                                               const _Float16* __restrict__ B, int ldb,
                                               const float* __restrict__ bias,
                                               float* __restrict__ C, int ldc,
                                               int K, int Mstore) {
    __shared__ _Float16 As[128 * 32];
    __shared__ _Float16 Bs[128 * 32];
    const int rowBase = blockIdx.x * 128;
    const int colBase = blockIdx.y * 128;
    const int tid  = threadIdx.x;
    const int lane = tid & 63;
    const int w    = tid >> 6;
    const int wm = w & 1, wn = w >> 1;
    const int quad = lane >> 4, mr = lane & 15;

    float4_ acc[4][4];
#pragma unroll
    for (int i = 0; i < 4; i++)
#pragma unroll
        for (int j = 0; j < 4; j++) { float4_ z4 = {0.f, 0.f, 0.f, 0.f}; acc[i][j] = z4; }

    const int c0  = w * 64 + lane;
    const int rA0 = c0 >> 2;
    const int ko  = (c0 & 3) * 8;
    char* AsB = (char*)As;
    char* BsB = (char*)Bs;
    void* lA0 = AsB + w * 1024;
    void* lA1 = AsB + 4096 + w * 1024;
    void* lB0 = BsB + w * 1024;
    void* lB1 = BsB + 4096 + w * 1024;
    const _Float16* gA0 = A + (size_t)(rowBase + rA0) * lda + ko;
    const _Float16* gA1 = gA0 + (size_t)64 * lda;
    const _Float16* gB0 = B + (size_t)(colBase + rA0) * ldb + ko;
    const _Float16* gB1 = gB0 + (size_t)64 * ldb;

    for (int k0 = 0; k0 < K; k0 += 32) {
        gload16(gA0 + k0, lA0);
        gload16(gA1 + k0, lA1);
        gload16(gB0 + k0, lB0);
        gload16(gB1 + k0, lB1);
        __syncthreads();
        half8_ a[4], b[4];
#pragma unroll
        for (int im = 0; im < 4; im++)
            a[im] = *(const half8_*)(AsB + ((wm * 64 + im * 16 + mr) * 64 + quad * 16));
#pragma unroll
        for (int in = 0; in < 4; in++)
            b[in] = *(const half8_*)(BsB + ((wn * 64 + in * 16 + mr) * 64 + quad * 16));
#pragma unroll
        for (int im = 0; im < 4; im++)
#pragma unroll
            for (int in = 0; in < 4; in++)
                acc[im][in] = __builtin_amdgcn_mfma_f32_16x16x32_f16(a[im], b[in], acc[im][in], 0, 0, 0);
        __syncthreads();
    }

#pragma unroll
    for (int in = 0; in < 4; in++) {
        const int colg = colBase + wn * 64 + in * 16 + mr;
        const float bv = bias[colg];
#pragma unroll
        for (int im = 0; im < 4; im++) {
            float4_ c = acc[im][in];
#pragma unroll
            for (int r = 0; r < 4; r++) {
                int row = rowBase + wm * 64 + im * 16 + quad * 4 + r;
                if (row < Mstore) C[(size_t)row * ldc + colg] = c[r] + bv;
            }
        }
    }
}

extern "C" void kernel_launch(void* const* d_in, const int* in_sizes, int n_in,
                              void* d_out, int out_size, void* d_ws, size_t ws_size,
                              hipStream_t stream) {
    const float* x    = (const float*)d_in[0];
    const int*   e1   = (const int*)d_in[1];
    const int*   e2   = (const int*)d_in[2];
    const float* Wl   = (const float*)d_in[3];
    const float* bl   = (const float*)d_in[4];
    const float* W0   = (const float*)d_in[5];
    const float* b0   = (const float*)d_in[6];
    const float* W1   = (const float*)d_in[7];
    const float* b1   = (const float*)d_in[8];
    const float* gamma= (const float*)d_in[9];
    const float* beta = (const float*)d_in[10];
    const float* Wout = (const float*)d_in[11];
    const float* bout = (const float*)d_in[12];

    char* ws = (char*)d_ws;
    size_t off = 0;
    auto alloc = [&](size_t bytes) -> char* {
        char* p = ws + off;
        off = (off + bytes + 255) & ~(size_t)255;
        return p;
    };
    _Float16* xh   = (_Float16*)alloc((size_t)NPAD * 256 * 2);
    _Float16* aggb = (_Float16*)alloc((size_t)NPAD * 256 * 2);
    _Float16* h1   = (_Float16*)alloc((size_t)NPAD * 256 * 2);
    _Float16* h2   = (_Float16*)alloc((size_t)NPAD * 256 * 2);
    _Float16* Wcat = (_Float16*)alloc((size_t)(2 * 256 * 768 + 128 * 256) * 2);
    float*    bias = (float*)alloc(640 * 4);
    int* cnt   = (int*)alloc((size_t)2 * N_NODES * 4);
    int* rp    = (int*)alloc((size_t)2 * (N_NODES + 1) * 4);
    int* ranks = (int*)alloc((size_t)2 * N_EDGES * 4);
    int* col   = (int*)alloc((size_t)2 * N_EDGES * 4);
    int* bsums = (int*)alloc(512 * 4);

    int* rp1 = rp, *rp2 = rp + (N_NODES + 1);
    int* col1 = col, *col2 = col + N_EDGES;

    hipMemsetAsync(cnt, 0, (size_t)2 * N_NODES * 4, stream);

    const int eb8 = (N_EDGES / 8 + 255) / 256;   // 245
    count_rank_kernel<<<dim3(eb8, 2), 256, 0, stream>>>(e1, e2, cnt, ranks, N_EDGES, N_NODES);
    bsum_kernel<<<dim3(NB, 2), 256, 0, stream>>>(cnt, bsums, N_NODES);
    bscan_kernel<<<1, 512, 0, stream>>>(bsums, rp1, rp2, NB, N_NODES);
    bscatter_kernel<<<dim3(NB, 2), 256, 0, stream>>>(cnt, bsums, rp, N_NODES);
    place_kernel<<<dim3(eb8, 2), 256, 0, stream>>>(e1, e2, ranks, rp, col, N_EDGES, N_NODES);

    copyx_kernel<<<12500, 256, 0, stream>>>(x, xh, N_NODES);
    pad_kernel<<<48, 256, 0, stream>>>(xh, aggb, h1, h2);
    wcat_kernel<<<(2 * 256 * 768 + 128 * 256 + 255) / 256, 256, 0, stream>>>(Wl, W0, W1, Wout, Wcat);
    bias_kernel<<<3, 256, 0, stream>>>(bl, b0, b1, bout, bias);

    const int nb4 = (N_NODES + 3) / 4;

    // ----- layer 1: weights idx 1, edges r2, h_in = x -----
    gather_kernel<<<nb4, 256, 0, stream>>>(xh, rp2, col2, aggb, N_NODES);
    gemm_ln<<<391, 512, 0, stream>>>(aggb, xh, xh, Wcat + 196608,
                                     bias + 256, gamma + 256, beta + 256, h1);

    // ----- layer 2: weights idx 0, edges r1, h_in = h1 -----
    gather_kernel<<<nb4, 256, 0, stream>>>(h1, rp1, col1, aggb, N_NODES);
    gemm_ln<<<391, 512, 0, stream>>>(aggb, h1, xh, Wcat,
                                     bias, gamma, beta, h2);

    // ----- output: d_out = h2 @ Wout^T + bout (fp32) -----
    gemm_bt<<<dim3(391, 1), 256, 0, stream>>>(h2, 256, Wcat + 393216, 256,
                                              bias + 512, (float*)d_out, 128, 256, N_NODES);
}